// Round 6
// baseline (1425.297 us; speedup 1.0000x reference)
//
#include <hip/hip_runtime.h>
#include <math.h>

#define BATCH 8
#define WID   32
#define NX    64
#define NY    64
#define NT    40
#define M1C   12
#define KT    8      // M3
#define KXC   24
#define KYC   24
#define NXY   (NX*NY)        // 4096
#define NXYT  (NXY*NT)       // 163840
#define NP    (BATCH*NXYT)   // 1310720

#define TWO_PI 6.283185307179586f

static __device__ __forceinline__ float gelu_f(float v){
  return 0.5f*v*(1.0f + erff(v*0.7071067811865476f));
}

// barrier that does NOT drain vmcnt (keeps global prefetch loads in flight).
static __device__ __forceinline__ void barrier_lds(){
  asm volatile("s_waitcnt lgkmcnt(0)\n\ts_barrier" ::: "memory");
}

// V layout throughout: [b][x][y][t][c]  (channel-innermost, plane = 1280 floats)
// R11: k_fc0 DELETED — the 5->32 lift is linear and recomputed inline by the
// two V consumers of layer 0 (fwd_ty<LIFT> and k_conv<*,LIFT>) from h/x +
// a 1KB LDS weight table wT[c][{w0..w4,b}]. Saves the fc0 dispatch + the
// 168MB V read in fwd_ty L0 + the V-plane prefetch in k_conv L0.

// ------- fused forward T+Y per (b,x): V slice -> F2 [bc*64+x][ky*8+kt] -------
// Structure = R10 (512 thr, even/odd halves, R9 data path: transposed [c][t]
// pitch-42 staging, radix-2 butterfly folded into staging, b64 T-reads,
// register global prefetch). LIFT=true (L0): staging computes the lift from
// h/x; butterfly: u = 2b + sum((in_t+in_t20)*w), d = sum((in_t-in_t20)*w).
template<bool LIFT>
__global__ __launch_bounds__(512) void k_fwd_ty(const float* __restrict__ V, float2* __restrict__ F2,
                                                const float* __restrict__ hin, const float* __restrict__ xin,
                                                const float* __restrict__ lw, const float* __restrict__ lb){
  __shared__ __align__(16) unsigned char smem[56320];
  // buf[h][p] at h*21504 + p*10752 ([2y][32c][42] = 10752 B each)
  float2* twy   = (float2*)(smem+43008);        // [24][64] = 12288 B
  float2* f2out = (float2*)smem;                // epilogue alias: 32*193*8 = 49408 B
  float*  wTl   = (float*)(smem+55296);         // [32][8] lift weights = 1024 B
  int tid = threadIdx.x;
  int h = tid >> 8, t8 = tid & 255;
  int b = blockIdx.x >> 6, x = blockIdx.x & 63;
  int c = t8 & 31, k = t8 >> 5;
  if constexpr(LIFT){
    if(tid<192){ int cc=tid/6, i=tid-6*cc; wTl[cc*8+i] = (i<5)? lw[i*32+cc] : lb[cc]; }
    __syncthreads();                     // wTl visible before first staging
  }
  for(int i=tid;i<KYC*NY;i+=512){
    int ky=i>>6, y=i&63;
    int f = ky<M1C ? ky : ky+40;
    float ang = -TWO_PI*(float)((f*y)%NY)/(float)NY;
    twy[i] = make_float2(cosf(ang), sinf(ang));
  }
  // per-thread T-twiddle HALF-row (radix-2)
  float2 twr[20];
  #pragma unroll
  for(int t=0;t<20;t++){
    float ang = -TWO_PI*(float)((k*t)%NT)/(float)NT;
    twr[t] = make_float2(cosf(ang), sinf(ang));
  }
  int toff = (k&1)*20;                     // even k -> u half, odd k -> d half
  float2 acc[KYC];
  #pragma unroll
  for(int q=0;q<KYC;q++) acc[q]=make_float2(0.f,0.f);
  const float4* src = (const float4*)(V + (size_t)(b*NX+x)*(NY*NT*WID));
  const float* hb = hin + (size_t)(b*NX+x)*(NY*NT)*2;
  const float* xb = xin + (size_t)(b*NX+x)*(NY*NT)*3;
  float* myb0 = (float*)(smem + h*21504);
  float* myb1 = myb0 + 2688;               // +10752 B

  // staging slots for a 2-y group: s in [0,320) = [yl 2][t 20][c4 8]
  int s0 = t8;
  int c40 = s0&7, t0s = (s0>>3)%20, yl0 = s0/160;
  bool has1 = (t8 < 64);
  int s1 = t8 + 256;
  int c41 = s1&7, t1s = (s1>>3)%20, yl1 = s1/160;

  float4 pa0, pb0, pa1, pb1;               // non-LIFT prefetch
  float2 hA0,hB0,hA1,hB1;                  // LIFT prefetch
  float xA00,xA01,xA02,xB00,xB01,xB02;
  float xA10,xA11,xA12,xB10,xB11,xB12;

#define TY_LOAD(G) do{ \
    if constexpr(LIFT){ \
      { size_t pt = (size_t)((2*(G)+yl0)*40 + t0s); \
        hA0 = *(const float2*)(hb + pt*2); \
        hB0 = *(const float2*)(hb + (pt+20)*2); \
        xA00 = xb[pt*3]; xA01 = xb[pt*3+1]; xA02 = xb[pt*3+2]; \
        xB00 = xb[(pt+20)*3]; xB01 = xb[(pt+20)*3+1]; xB02 = xb[(pt+20)*3+2]; } \
      if(has1){ size_t pt = (size_t)((2*(G)+yl1)*40 + t1s); \
        hA1 = *(const float2*)(hb + pt*2); \
        hB1 = *(const float2*)(hb + (pt+20)*2); \
        xA10 = xb[pt*3]; xA11 = xb[pt*3+1]; xA12 = xb[pt*3+2]; \
        xB10 = xb[(pt+20)*3]; xB11 = xb[(pt+20)*3+1]; xB12 = xb[(pt+20)*3+2]; } \
    } else { \
      pa0 = src[(2*(G) + yl0)*320 + t0s*8 + c40]; \
      pb0 = src[(2*(G) + yl0)*320 + t0s*8 + c40 + 160]; \
      if(has1){ \
        pa1 = src[(2*(G) + yl1)*320 + t1s*8 + c41]; \
        pb1 = src[(2*(G) + yl1)*320 + t1s*8 + c41 + 160]; \
      } \
    } \
  }while(0)

#define TY_STAGE(BUF) do{ \
    if constexpr(LIFT){ \
      float su0=hA0.x+hB0.x, su1=hA0.y+hB0.y, su2=xA00+xB00, su3=xA01+xB01, su4=xA02+xB02; \
      float sd0=hA0.x-hB0.x, sd1=hA0.y-hB0.y, sd2=xA00-xB00, sd3=xA01-xB01, sd4=xA02-xB02; \
      float* bse = (BUF) + yl0*1344 + t0s; \
      _Pragma("unroll") \
      for(int e=0;e<4;e++){ \
        const float* wr = wTl + (4*c40+e)*8; \
        float4 w03 = *(const float4*)wr; float2 w45 = *(const float2*)(wr+4); \
        bse[(4*c40+e)*42]      = 2.f*w45.y + su0*w03.x + su1*w03.y + su2*w03.z + su3*w03.w + su4*w45.x; \
        bse[(4*c40+e)*42 + 20] = sd0*w03.x + sd1*w03.y + sd2*w03.z + sd3*w03.w + sd4*w45.x; \
      } \
      if(has1){ \
        float tu0=hA1.x+hB1.x, tu1=hA1.y+hB1.y, tu2=xA10+xB10, tu3=xA11+xB11, tu4=xA12+xB12; \
        float td0=hA1.x-hB1.x, td1=hA1.y-hB1.y, td2=xA10-xB10, td3=xA11-xB11, td4=xA12-xB12; \
        float* bs1 = (BUF) + yl1*1344 + t1s; \
        _Pragma("unroll") \
        for(int e=0;e<4;e++){ \
          const float* wr = wTl + (4*c41+e)*8; \
          float4 w03 = *(const float4*)wr; float2 w45 = *(const float2*)(wr+4); \
          bs1[(4*c41+e)*42]      = 2.f*w45.y + tu0*w03.x + tu1*w03.y + tu2*w03.z + tu3*w03.w + tu4*w45.x; \
          bs1[(4*c41+e)*42 + 20] = td0*w03.x + td1*w03.y + td2*w03.z + td3*w03.w + td4*w45.x; \
        } \
      } \
    } else { \
      float* bse = (BUF) + yl0*1344 + t0s; \
      _Pragma("unroll") \
      for(int e=0;e<4;e++){ \
        float av=((float*)&pa0)[e], bv=((float*)&pb0)[e]; \
        bse[(4*c40+e)*42]      = av+bv; \
        bse[(4*c40+e)*42 + 20] = av-bv; \
      } \
      if(has1){ \
        float* bs1 = (BUF) + yl1*1344 + t1s; \
        _Pragma("unroll") \
        for(int e=0;e<4;e++){ \
          float av=((float*)&pa1)[e], bv=((float*)&pb1)[e]; \
          bs1[(4*c41+e)*42]      = av+bv; \
          bs1[(4*c41+e)*42 + 20] = av-bv; \
        } \
      } \
    } \
  }while(0)

  // ---- prologue: group g=h -> myb0; prefetch group h+2 ----
  TY_LOAD(h);
  TY_STAGE(myb0);
  TY_LOAD(h+2);
  __syncthreads();                         // my buf0 + twy visible

  #pragma unroll 1
  for(int it=0; it<16; ++it){
    int g = 2*it + h;                      // h=0: even groups, h=1: odd; union = all 32
    const float* vb = (it&1) ? myb1 : myb0;
    float*       vn = (it&1) ? myb0 : myb1;
    if(it+1<16){                           // stage group g+2 (regs -> vn)
      TY_STAGE(vn);
      if(it+2<16){                         // issue loads for group g+4
        TY_LOAD(g+4);
      }
    }
    // compute the 2 y of group g
    {
      const float* vp0 = vb + c*42 + toff;
      const float* vp1 = vp0 + 1344;
      float sr0=0.f,si0=0.f,sr1=0.f,si1=0.f;
      #pragma unroll
      for(int i5=0; i5<5; i5++){
        float2 a0 = *(const float2*)(vp0 + i5*4);
        float2 b0 = *(const float2*)(vp0 + i5*4 + 2);
        float2 a1 = *(const float2*)(vp1 + i5*4);
        float2 b1 = *(const float2*)(vp1 + i5*4 + 2);
        float2 w0=twr[i5*4], w1=twr[i5*4+1], w2=twr[i5*4+2], w3=twr[i5*4+3];
        sr0 += a0.x*w0.x + a0.y*w1.x + b0.x*w2.x + b0.y*w3.x;
        si0 += a0.x*w0.y + a0.y*w1.y + b0.x*w2.y + b0.y*w3.y;
        sr1 += a1.x*w0.x + a1.y*w1.x + b1.x*w2.x + b1.y*w3.x;
        si1 += a1.x*w0.y + a1.y*w1.y + b1.x*w2.y + b1.y*w3.y;
      }
      int y = 2*g;                         // even -> float4 twy pair aligned
      #pragma unroll
      for(int q=0;q<KYC;q++){
        float4 wy = *(const float4*)&twy[q*NY + y];   // (w_y, w_{y+1}) broadcast
        acc[q].x += sr0*wy.x - si0*wy.y + sr1*wy.z - si1*wy.w;
        acc[q].y += sr0*wy.y + si0*wy.x + sr1*wy.w + si1*wy.z;
      }
    }
    barrier_lds();                         // one barrier per group-step
  }
  // epilogue merge: buffers/twy dead after final barrier -> f2out alias safe
  if(h==0){
    #pragma unroll
    for(int q=0;q<KYC;q++) f2out[c*193 + q*8 + k] = acc[q];
  }
  __syncthreads();
  if(h==1){
    #pragma unroll
    for(int q=0;q<KYC;q++){
      float2 v = f2out[c*193 + q*8 + k];
      f2out[c*193 + q*8 + k] = make_float2(v.x+acc[q].x, v.y+acc[q].y);
    }
  }
  __syncthreads();
  for(int i=tid;i<WID*KYC*KT;i+=512){
    int cc=i/192, e=i-cc*192;
    F2[((size_t)(b*WID+cc)*NX + x)*(KYC*KT) + e] = f2out[cc*193 + e];
  }
#undef TY_LOAD
#undef TY_STAGE
}

// ---------------- forward X: F2 -> F3 [B,32,24,24,8] cplx ----------------
__global__ __launch_bounds__(256) void k_fwd_x(const float2* __restrict__ F2, float2* __restrict__ F3){
  __shared__ float2 tile[NX*KT];
  __shared__ float2 twi[KXC*65];          // stride 65 cplx
  int tid=threadIdx.x;
  int bc = blockIdx.x / KYC;
  int ky = blockIdx.x - bc*KYC;
  for(int i=tid;i<NX*KT;i+=256){
    int xx=i/KT, kt=i-xx*KT;
    tile[i] = F2[((size_t)bc*NX + xx)*(KYC*KT) + ky*KT + kt];
  }
  for(int i=tid;i<KXC*NX;i+=256){
    int kx=i/NX, xx=i-kx*NX;
    int f = kx<M1C ? kx : kx+40;
    float ang = -TWO_PI*(float)((f*xx)%NX)/(float)NX;
    twi[kx*65+xx] = make_float2(cosf(ang), sinf(ang));
  }
  __syncthreads();
  for(int item=tid; item<KXC*KT; item+=256){
    int kx=item/KT, kt=item-kx*KT;
    float sr=0.f, si=0.f;
    #pragma unroll 8
    for(int xx=0;xx<NX;xx++){
      float2 a = tile[xx*KT+kt];
      float2 w = twi[kx*65+xx];
      sr += a.x*w.x - a.y*w.y;
      si += a.x*w.y + a.y*w.x;
    }
    F3[(size_t)bc*(KXC*KYC*KT) + kx*(KYC*KT) + ky*KT + kt] = make_float2(sr,si);
  }
}

// ---------------- channel mix: F3 -> F4 ----------------
__global__ __launch_bounds__(256) void k_mix(const float2* __restrict__ F3, const float* __restrict__ wr,
                                             const float* __restrict__ wi, float2* __restrict__ F4){
  __shared__ float2 f3s[BATCH*WID*KT];     // [b][i][kt] = 16 KB
  int tid = threadIdx.x;
  int kx = blockIdx.x / KYC, ky = blockIdx.x - kx*KYC;
  int mode0 = blockIdx.x * KT;
  int xp = (kx>=M1C), yp = (ky>=M1C);
  int m1 = kx - M1C*xp, m2 = ky - M1C*yp;
  int blk = xp + 2*yp;
  for(int i=tid;i<1024;i+=256){
    int row=i>>2, q=i&3;
    ((float4*)f3s)[row*4+q] = ((const float4*)(F3 + (size_t)row*4608 + mode0))[q];
  }
  int o = tid>>3, kt = tid&7;
  size_t wbase = (size_t)blk*1179648 + (size_t)o*1152 + m1*96 + m2*8 + kt;
  float wre[WID], wim[WID];
  #pragma unroll
  for(int i=0;i<WID;i++){
    wre[i] = wr[wbase + (size_t)i*36864];
    wim[i] = wi[wbase + (size_t)i*36864];
  }
  __syncthreads();
  #pragma unroll
  for(int b=0;b<BATCH;b++){
    float ar=0.f, ai=0.f;
    #pragma unroll
    for(int i=0;i<WID;i++){
      float2 a = f3s[(b*WID+i)*KT + kt];
      ar += a.x*wre[i] - a.y*wim[i];
      ai += a.x*wim[i] + a.y*wre[i];
    }
    F4[(size_t)(b*WID+o)*4608 + mode0 + kt] = make_float2(ar,ai);
  }
}

// ---------------- inverse X: F4 -> F2 (1/64 folded) ----------------
__global__ __launch_bounds__(256) void k_inv_x(const float2* __restrict__ F4, float2* __restrict__ F2){
  __shared__ float2 tile[KXC*KT];
  __shared__ float2 twi[NX*25];
  int tid=threadIdx.x;
  int bc = blockIdx.x / KYC, ky = blockIdx.x - (blockIdx.x/KYC)*KYC;
  for(int i=tid;i<KXC*KT;i+=256){
    int kx=i/KT, kt=i-kx*KT;
    tile[i] = F4[(size_t)bc*4608 + kx*(KYC*KT) + ky*KT + kt];
  }
  for(int i=tid;i<NX*KXC;i+=256){
    int xx=i/KXC, kx=i-xx*KXC;
    int f = kx<M1C ? kx : kx+40;
    float ang = TWO_PI*(float)((f*xx)%NX)/(float)NX;
    twi[xx*25+kx] = make_float2(cosf(ang)*(1.0f/64.0f), sinf(ang)*(1.0f/64.0f));
  }
  __syncthreads();
  for(int item=tid; item<NX*KT; item+=256){
    int xx=item/KT, kt=item-xx*KT;
    float sr=0.f, si=0.f;
    #pragma unroll 8
    for(int kx=0;kx<KXC;kx++){
      float2 a = tile[kx*KT+kt];
      float2 w = twi[xx*25+kx];
      sr += a.x*w.x - a.y*w.y;
      si += a.x*w.y + a.y*w.x;
    }
    F2[((size_t)bc*NX + xx)*(KYC*KT) + ky*KT + kt] = make_float2(sr,si);
  }
}

// ------- fused inv-Y + irfft-T + conv1x1 [+gelu], in-place on V -------
// grid = B*NX*2, block = (b, x, y-half). R7 schedule (proven). LIFT=true (L0):
// the conv1x1 input plane is recomputed from h/x + wTl instead of read from V
// (V is first WRITTEN by this kernel's L0 output). No min-waves clamp (R3-R5).
template<bool GELU, bool LIFT>
__global__ __launch_bounds__(256) void k_conv(const float2* __restrict__ F2, const float* __restrict__ wcv,
                                              const float* __restrict__ bcv, float* __restrict__ V,
                                              const float* __restrict__ hin, const float* __restrict__ xin,
                                              const float* __restrict__ lw, const float* __restrict__ lb){
  __shared__ __align__(16) unsigned char smem[35840];
  float*  vtA  = (float*)smem;                  // [2][1280] = 10240 B
  float*  vtB  = (float*)(smem+10240);          // [2][1280] = 10240 B
  float2* ftc0 = (float2*)(smem+20480);         // [2][256]  =  4096 B
  float2* ftc1 = (float2*)(smem+24576);         // [2][256]  =  4096 B
  float2* twy  = (float2*)(smem+28672);         // [32][24]  =  6144 B
  float*  wTl  = (float*)(smem+34816);          // [32][8] lift weights = 1024 B
  float2* f2h  = (float2*)smem;                 // prologue alias: 24576 B

  int tid=threadIdx.x;
  int b  = blockIdx.x >> 7;
  int x  = (blockIdx.x >> 1) & 63;
  int y0 = (blockIdx.x & 1) * 32;
  int cid = tid & 31, ktid = tid >> 5;   // inv-Y identity
  int oid = tid & 31, tg  = tid >> 5;    // conv identity; t = tg*5+j

  if constexpr(LIFT){
    if(tid<192){ int cc=tid/6, i=tid-6*cc; wTl[cc*8+i] = (i<5)? lw[i*32+cc] : lb[cc]; }
    // visibility covered by the prologue __syncthreads below
  }

  // ---- prologue: F2 slice -> registers via LDS (two halves) ----
  float2 fr[KYC];
  #pragma unroll
  for(int half=0; half<2; half++){
    for(int i=tid;i<1536;i+=256){
      int cc=i/96, q=i-cc*96;
      ((float4*)f2h)[i] = *((const float4*)(F2 + ((size_t)(b*WID + half*16 + cc)*NX + x)*(KYC*KT)) + q);
    }
    __syncthreads();
    if((cid>>4) == half){
      const float2* fp = f2h + (cid&15)*192 + ktid;
      #pragma unroll
      for(int ky=0;ky<KYC;ky++) fr[ky] = fp[ky*8];
    }
    __syncthreads();
  }
  // fold irfft-T scale (k==0?1:2)/NT into fr (linear through inv-Y)
  {
    float ts = (ktid==0 ? 1.0f : 2.0f) * (1.0f/(float)NT);
    #pragma unroll
    for(int ky=0;ky<KYC;ky++){ fr[ky].x *= ts; fr[ky].y *= ts; }
  }
  float wreg[WID];
  #pragma unroll
  for(int cc=0;cc<WID;cc++) wreg[cc] = wcv[oid*WID + cc];
  float breg = bcv[oid];
  // per-thread T-twiddle base: e^{i*pi/4*(k*tg mod 8)}  (t = 5*tg + j)
  float2 twtg[KT];
  #pragma unroll
  for(int k=0;k<KT;k++){
    float ang = 0.78539816339744831f*(float)((k*tg)&7);
    twtg[k] = make_float2(cosf(ang), sinf(ang));
  }
  for(int i=tid;i<32*KYC;i+=256){
    int yy=i/KYC, ky=i-yy*KYC;
    int f = ky<M1C ? ky : ky+40;
    float ang = TWO_PI*(float)((f*(y0+yy))%NY)/(float)NY;
    twy[i] = make_float2(cosf(ang)*(1.0f/64.0f), sinf(ang)*(1.0f/64.0f));
  }
  float* plane = V + (size_t)((b*NX+x)*NY + y0)*(NT*WID);
  const float4* gp = (const float4*)plane;
  const float* hbc = hin + (size_t)((b*NX+x)*NY + y0)*NT*2;
  const float* xbc = xin + (size_t)((b*NX+x)*NY + y0)*NT*3;
  bool has3 = tid < 128;
  // slot decomposition for LIFT staging: 640 f4-slots = [yy 2][t 40][c4 8]
  int t0c = tid>>3;                        // slot tid      (yy=0)
  int yy1c = (tid>=64);                    // slot tid+256
  int t1c = yy1c ? ((tid-64)>>3) : ((tid+256)>>3);
  int t2c = (tid+192)>>3;                  // slot tid+512  (yy=1, tid<128)
  int c4c = tid&7;                         // same c4 for all three slots

  float4 rA, rB, rC;                       // non-LIFT prefetch
  float2 hC0, hC1, hC2;                    // LIFT prefetch
  float xC00,xC01,xC02,xC10,xC11,xC12,xC20,xC21,xC22;

#define CV_LOAD(P) do{ \
    if constexpr(LIFT){ \
      { size_t pt = (size_t)((2*(P))*40 + t0c); \
        hC0 = *(const float2*)(hbc + pt*2); \
        xC00 = xbc[pt*3]; xC01 = xbc[pt*3+1]; xC02 = xbc[pt*3+2]; } \
      { size_t pt = (size_t)((2*(P)+yy1c)*40 + t1c); \
        hC1 = *(const float2*)(hbc + pt*2); \
        xC10 = xbc[pt*3]; xC11 = xbc[pt*3+1]; xC12 = xbc[pt*3+2]; } \
      if(has3){ size_t pt = (size_t)((2*(P)+1)*40 + t2c); \
        hC2 = *(const float2*)(hbc + pt*2); \
        xC20 = xbc[pt*3]; xC21 = xbc[pt*3+1]; xC22 = xbc[pt*3+2]; } \
    } else { \
      const float4* q = gp + (size_t)(P)*640; \
      rA = q[tid]; rB = q[256+tid]; \
      if(has3) rC = q[512+tid]; \
    } \
  }while(0)

#define CV_STAGE(BUF) do{ \
    if constexpr(LIFT){ \
      float4 v0, v1, v2; \
      _Pragma("unroll") \
      for(int e=0;e<4;e++){ \
        const float* wr = wTl + (4*c4c+e)*8; \
        float4 w03 = *(const float4*)wr; float2 w45 = *(const float2*)(wr+4); \
        ((float*)&v0)[e] = w45.y + hC0.x*w03.x + hC0.y*w03.y + xC00*w03.z + xC01*w03.w + xC02*w45.x; \
        ((float*)&v1)[e] = w45.y + hC1.x*w03.x + hC1.y*w03.y + xC10*w03.z + xC11*w03.w + xC12*w45.x; \
        if(has3) ((float*)&v2)[e] = w45.y + hC2.x*w03.x + hC2.y*w03.y + xC20*w03.z + xC21*w03.w + xC22*w45.x; \
      } \
      ((float4*)(BUF))[tid] = v0; \
      ((float4*)(BUF))[256+tid] = v1; \
      if(has3) ((float4*)(BUF))[512+tid] = v2; \
    } else { \
      ((float4*)(BUF))[tid] = rA; \
      ((float4*)(BUF))[256+tid] = rB; \
      if(has3) ((float4*)(BUF))[512+tid] = rC; \
    } \
  }while(0)

  // stage pair 0 into vtA; prefetch pair 1 into regs
  CV_LOAD(0);
  CV_STAGE(vtA);
  CV_LOAD(1);
  __syncthreads();                        // publish vtA + twy (+wTl) (prologue only)

  // cos/sin(pi*k*j/20) — compile-time literals (fold into v_fmac immediates)
  constexpr float CJ[KT][5] = {
    {1.f, 1.f,          1.f,          1.f,          1.f         },
    {1.f, 0.98768834f,  0.95105652f,  0.89100652f,  0.80901699f },
    {1.f, 0.95105652f,  0.80901699f,  0.58778525f,  0.30901699f },
    {1.f, 0.89100652f,  0.58778525f,  0.15643447f, -0.30901699f },
    {1.f, 0.80901699f,  0.30901699f, -0.30901699f, -0.80901699f },
    {1.f, 0.70710678f,  0.f,         -0.70710678f, -1.f         },
    {1.f, 0.58778525f, -0.30901699f, -0.95105652f, -0.80901699f },
    {1.f, 0.45399050f, -0.58778525f, -0.98768834f, -0.30901699f },
  };
  constexpr float SJ[KT][5] = {
    {0.f, 0.f,          0.f,          0.f,          0.f         },
    {0.f, 0.15643447f,  0.30901699f,  0.45399050f,  0.58778525f },
    {0.f, 0.30901699f,  0.58778525f,  0.80901699f,  0.95105652f },
    {0.f, 0.45399050f,  0.80901699f,  0.98768834f,  0.95105652f },
    {0.f, 0.58778525f,  0.95105652f,  0.95105652f,  0.58778525f },
    {0.f, 0.70710678f,  1.f,          0.70710678f,  0.f         },
    {0.f, 0.80901699f,  0.95105652f,  0.30901699f, -0.58778525f },
    {0.f, 0.89100652f,  0.80901699f, -0.15643447f, -0.95105652f },
  };

  #pragma unroll 1
  for(int it=0; it<16; ++it){
    float*  vcur = (it&1) ? vtB  : vtA;
    float*  vnxt = (it&1) ? vtA  : vtB;
    float2* fcur = (it&1) ? ftc1 : ftc0;
    int yl = it*2;
    { // inverse-Y for y=yl and yl+1, interleaved chains, b128 ky-pair twiddles
      const float2* tw0 = twy + (size_t)yl*KYC;
      const float2* tw1 = tw0 + KYC;
      float sr0=0.f, si0=0.f, sr1=0.f, si1=0.f;
      #pragma unroll
      for(int ky=0;ky<KYC;ky+=2){
        float2 a  = fr[ky];
        float2 b2 = fr[ky+1];
        float4 w0 = *(const float4*)&tw0[ky];
        float4 w1 = *(const float4*)&tw1[ky];
        sr0 += a.x*w0.x - a.y*w0.y + b2.x*w0.z - b2.y*w0.w;
        si0 += a.x*w0.y + a.y*w0.x + b2.x*w0.w + b2.y*w0.z;
        sr1 += a.x*w1.x - a.y*w1.y + b2.x*w1.z - b2.y*w1.w;
        si1 += a.x*w1.y + a.y*w1.x + b2.x*w1.w + b2.y*w1.z;
      }
      fcur[      ktid*32 + cid] = make_float2(sr0,si0);
      fcur[256 + ktid*32 + cid] = make_float2(sr1,si1);
    }
    barrier_lds();                        // the ONLY barrier per iteration
    // stage pair it+1 (regs -> vnxt) BEFORE this iteration's stores
    if(it+1 < 16){
      CV_STAGE(vnxt);
    }
    if(it+2 < 16){                        // issue loads for pair it+2
      CV_LOAD(it+2);
    }
    #pragma unroll
    for(int yy=0; yy<2; yy++){            // conv1x1 + irfft-T for the two y
      const float2* fsrc = fcur + yy*256;
      const float*  vb   = vcur + yy*1280;
      float* outp = plane + (size_t)(yl+yy)*(NT*WID);
      float acc[5];
      #pragma unroll
      for(int j=0;j<5;j++) acc[j] = breg;
      #pragma unroll
      for(int k=0;k<KT;k++){              // rotate mode by twtg, then literal DFT
        float2 f = fsrc[k*32 + oid];
        float gx = f.x*twtg[k].x - f.y*twtg[k].y;
        float gy = f.x*twtg[k].y + f.y*twtg[k].x;
        #pragma unroll
        for(int j=0;j<5;j++) acc[j] += gx*CJ[k][j] - gy*SJ[k][j];
      }
      #pragma unroll
      for(int j=0;j<5;j++){
        int t = tg*5 + j;
        float a = acc[j];
        const float* vrow = vb + t*32;
        #pragma unroll
        for(int c4=0;c4<WID;c4+=4){
          float4 vv = *(const float4*)(vrow + c4);   // broadcast b128
          a += vv.x*wreg[c4] + vv.y*wreg[c4+1] + vv.z*wreg[c4+2] + vv.w*wreg[c4+3];
        }
        outp[t*32 + oid] = GELU ? gelu_f(a) : a;     // lanes 0-31: one full 128B line
      }
    }
  }
#undef CV_LOAD
#undef CV_STAGE
}

// ---------------- fused fc1+gelu+fc2: V -> out [B,X,Y,T,2] ----------------
__global__ __launch_bounds__(256) void k_mlp(const float* __restrict__ V, const float* __restrict__ w1,
                                             const float* __restrict__ b1, const float* __restrict__ w2,
                                             const float* __restrict__ b2, float* __restrict__ out){
  __shared__ float sw1t[64*WID];          // [j][c]
  __shared__ float sb1[64], sw2[128], sb2[2];
  int tid=threadIdx.x;
  for(int i=tid;i<64*WID;i+=256){ int j=i>>5, c=i&31; sw1t[i]=w1[c*64+j]; }
  if(tid<64) sb1[tid]=b1[tid];
  if(tid<128) sw2[tid]=w2[tid];
  if(tid<2) sb2[tid]=b2[tid];
  __syncthreads();
  size_t p0 = (size_t)blockIdx.x*1024 + (size_t)tid*4;
  float vv[128];
  const float4* vp = (const float4*)(V + p0*WID);
  #pragma unroll
  for(int q=0;q<32;q++) *((float4*)(vv+4*q)) = vp[q];
  float oa[8];
  #pragma unroll
  for(int pt=0;pt<4;pt++){ oa[2*pt]=sb2[0]; oa[2*pt+1]=sb2[1]; }
  #pragma unroll 4
  for(int j=0;j<64;j++){
    float a0=sb1[j], a1=a0, a2=a0, a3=a0;
    const float* wrow = sw1t + j*WID;
    #pragma unroll
    for(int c4=0;c4<WID;c4+=4){
      float4 w = *(const float4*)(wrow + c4);        // broadcast b128
      a0 += vv[     c4]*w.x + vv[     c4+1]*w.y + vv[     c4+2]*w.z + vv[     c4+3]*w.w;
      a1 += vv[32 + c4]*w.x + vv[32 + c4+1]*w.y + vv[32 + c4+2]*w.z + vv[32 + c4+3]*w.w;
      a2 += vv[64 + c4]*w.x + vv[64 + c4+1]*w.y + vv[64 + c4+2]*w.z + vv[64 + c4+3]*w.w;
      a3 += vv[96 + c4]*w.x + vv[96 + c4+1]*w.y + vv[96 + c4+2]*w.z + vv[96 + c4+3]*w.w;
    }
    a0=gelu_f(a0); a1=gelu_f(a1); a2=gelu_f(a2); a3=gelu_f(a3);
    float u0=sw2[2*j], u1=sw2[2*j+1];
    oa[0]+=a0*u0; oa[1]+=a0*u1; oa[2]+=a1*u0; oa[3]+=a1*u1;
    oa[4]+=a2*u0; oa[5]+=a2*u1; oa[6]+=a3*u0; oa[7]+=a3*u1;
  }
  float4* op = (float4*)(out + p0*2);
  op[0]=make_float4(oa[0],oa[1],oa[2],oa[3]);
  op[1]=make_float4(oa[4],oa[5],oa[6],oa[7]);
}

extern "C" void kernel_launch(void* const* d_in, const int* in_sizes, int n_in,
                              void* d_out, int out_size, void* d_ws, size_t ws_size,
                              hipStream_t stream){
  const float* h     = (const float*)d_in[0];
  const float* x     = (const float*)d_in[1];
  const float* fc0_w = (const float*)d_in[2];
  const float* fc0_b = (const float*)d_in[3];
  const float* scwr[3] = {(const float*)d_in[4], (const float*)d_in[6], (const float*)d_in[8]};
  const float* scwi[3] = {(const float*)d_in[5], (const float*)d_in[7], (const float*)d_in[9]};
  const float* cw[3]   = {(const float*)d_in[10], (const float*)d_in[12], (const float*)d_in[14]};
  const float* cb[3]   = {(const float*)d_in[11], (const float*)d_in[13], (const float*)d_in[15]};
  const float* fc1_w = (const float*)d_in[16];
  const float* fc1_b = (const float*)d_in[17];
  const float* fc2_w = (const float*)d_in[18];
  const float* fc2_b = (const float*)d_in[19];

  // workspace: V (167.8 MB, layout [b,x,y,t,c]) | F2 (25.2 MB) | F4 (9.4 MB)
  // F3 lives in d_out (9.4 MB <= 10.5 MB) until k_mlp overwrites it.
  // R11: V is first written by k_conv L0 (fc0 lift fused into L0 consumers).
  const size_t VSZ = (size_t)BATCH*WID*NXYT;
  float*  V  = (float*)d_ws;
  float2* F2 = (float2*)(V + VSZ);
  float2* F4 = F2 + (size_t)BATCH*WID*NX*KYC*KT;
  float2* F3 = (float2*)d_out;

  for(int L=0; L<3; L++){
    if(L==0) k_fwd_ty<true ><<<BATCH*NX, 512, 0, stream>>>(V, F2, h, x, fc0_w, fc0_b);
    else     k_fwd_ty<false><<<BATCH*NX, 512, 0, stream>>>(V, F2, h, x, fc0_w, fc0_b);
    k_fwd_x<<<(BATCH*WID)*KYC, 256, 0, stream>>>(F2, F3);
    k_mix<<<KXC*KYC, 256, 0, stream>>>(F3, scwr[L], scwi[L], F4);
    k_inv_x<<<(BATCH*WID)*KYC, 256, 0, stream>>>(F4, F2);
    if(L==0)      k_conv<true ,true ><<<BATCH*NX*2, 256, 0, stream>>>(F2, cw[0], cb[0], V, h, x, fc0_w, fc0_b);
    else if(L==1) k_conv<true ,false><<<BATCH*NX*2, 256, 0, stream>>>(F2, cw[1], cb[1], V, h, x, fc0_w, fc0_b);
    else          k_conv<false,false><<<BATCH*NX*2, 256, 0, stream>>>(F2, cw[2], cb[2], V, h, x, fc0_w, fc0_b);
  }
  k_mlp<<<NP/1024, 256, 0, stream>>>(V, fc1_w, fc1_b, fc2_w, fc2_b, (float*)d_out);
}

// Round 7
// 1372.899 us; speedup vs baseline: 1.0382x; 1.0382x over previous
//
#include <hip/hip_runtime.h>
#include <math.h>

#define BATCH 8
#define WID   32
#define NX    64
#define NY    64
#define NT    40
#define M1C   12
#define KT    8      // M3
#define KXC   24
#define KYC   24
#define NXY   (NX*NY)        // 4096
#define NXYT  (NXY*NT)       // 163840
#define NP    (BATCH*NXYT)   // 1310720

#define TWO_PI 6.283185307179586f

static __device__ __forceinline__ float gelu_f(float v){
  return 0.5f*v*(1.0f + erff(v*0.7071067811865476f));
}

// barrier that does NOT drain vmcnt (keeps global prefetch loads in flight).
static __device__ __forceinline__ void barrier_lds(){
  asm volatile("s_waitcnt lgkmcnt(0)\n\ts_barrier" ::: "memory");
}

// V layout throughout: [b][x][y][t][c]  (channel-innermost, plane = 1280 floats)
// R11: k_fc0 DELETED — lift recomputed inline by the L0 consumers.
// R12: lift table re-laid out as wT2[c4][6][e] (float4 over channel-quad e).
//   R11's wTl[c][8] rows put all lanes of a fixed e on ONE bank (8-way
//   conflict, 31.6M SQ_LDS_BANK_CONFLICT, +52us on L0 conv). New layout:
//   b128 at byte 96*c4+16*i -> banks (24c4+4i)%32 = 2-way aliasing = free.

// ------- fused forward T+Y per (b,x): V slice -> F2 [bc*64+x][ky*8+kt] -------
// Structure = R10 (512 thr, even/odd halves, R9 data path). LIFT (L0): staging
// computes the 5->32 lift from h/x; u-half bias 2b is baked into the table.
template<bool LIFT>
__global__ __launch_bounds__(512) void k_fwd_ty(const float* __restrict__ V, float2* __restrict__ F2,
                                                const float* __restrict__ hin, const float* __restrict__ xin,
                                                const float* __restrict__ lw, const float* __restrict__ lb){
  __shared__ __align__(16) unsigned char smem[56320];
  // buf[h][p] at h*21504 + p*10752 ([2y][32c][42] = 10752 B each)
  float2* twy   = (float2*)(smem+43008);        // [24][64] = 12288 B
  float2* f2out = (float2*)smem;                // epilogue alias: 32*193*8 = 49408 B
  float*  wT2   = (float*)(smem+55296);         // [8 c4][6 i][4 e] = 768 B
  int tid = threadIdx.x;
  int h = tid >> 8, t8 = tid & 255;
  int b = blockIdx.x >> 6, x = blockIdx.x & 63;
  int c = t8 & 31, k = t8 >> 5;
  if constexpr(LIFT){
    if(tid<192){
      int c4=tid/24, rem=tid-24*c4, i=rem>>2, e=rem&3;
      wT2[tid] = (i<5)? lw[i*32 + 4*c4 + e] : 2.0f*lb[4*c4+e];   // 2x bias for u-half
    }
    __syncthreads();                     // wT2 visible before first staging
  }
  for(int i=tid;i<KYC*NY;i+=512){
    int ky=i>>6, y=i&63;
    int f = ky<M1C ? ky : ky+40;
    float ang = -TWO_PI*(float)((f*y)%NY)/(float)NY;
    twy[i] = make_float2(cosf(ang), sinf(ang));
  }
  // per-thread T-twiddle HALF-row (radix-2)
  float2 twr[20];
  #pragma unroll
  for(int t=0;t<20;t++){
    float ang = -TWO_PI*(float)((k*t)%NT)/(float)NT;
    twr[t] = make_float2(cosf(ang), sinf(ang));
  }
  int toff = (k&1)*20;                     // even k -> u half, odd k -> d half
  float2 acc[KYC];
  #pragma unroll
  for(int q=0;q<KYC;q++) acc[q]=make_float2(0.f,0.f);
  const float4* src = (const float4*)(V + (size_t)(b*NX+x)*(NY*NT*WID));
  const float* hb = hin + (size_t)(b*NX+x)*(NY*NT)*2;
  const float* xb = xin + (size_t)(b*NX+x)*(NY*NT)*3;
  float* myb0 = (float*)(smem + h*21504);
  float* myb1 = myb0 + 2688;               // +10752 B

  // staging slots for a 2-y group: s in [0,320) = [yl 2][t 20][c4 8]
  int s0 = t8;
  int c40 = s0&7, t0s = (s0>>3)%20, yl0 = s0/160;
  bool has1 = (t8 < 64);
  int s1 = t8 + 256;
  int c41 = s1&7, t1s = (s1>>3)%20, yl1 = s1/160;   // c41 == c40 (256%8==0)

  float4 pa0, pb0, pa1, pb1;               // non-LIFT prefetch
  float2 hA0,hB0,hA1,hB1;                  // LIFT prefetch
  float xA00,xA01,xA02,xB00,xB01,xB02;
  float xA10,xA11,xA12,xB10,xB11,xB12;

#define TY_LOAD(G) do{ \
    if constexpr(LIFT){ \
      { size_t pt = (size_t)((2*(G)+yl0)*40 + t0s); \
        hA0 = *(const float2*)(hb + pt*2); \
        hB0 = *(const float2*)(hb + (pt+20)*2); \
        xA00 = xb[pt*3]; xA01 = xb[pt*3+1]; xA02 = xb[pt*3+2]; \
        xB00 = xb[(pt+20)*3]; xB01 = xb[(pt+20)*3+1]; xB02 = xb[(pt+20)*3+2]; } \
      if(has1){ size_t pt = (size_t)((2*(G)+yl1)*40 + t1s); \
        hA1 = *(const float2*)(hb + pt*2); \
        hB1 = *(const float2*)(hb + (pt+20)*2); \
        xA10 = xb[pt*3]; xA11 = xb[pt*3+1]; xA12 = xb[pt*3+2]; \
        xB10 = xb[(pt+20)*3]; xB11 = xb[(pt+20)*3+1]; xB12 = xb[(pt+20)*3+2]; } \
    } else { \
      pa0 = src[(2*(G) + yl0)*320 + t0s*8 + c40]; \
      pb0 = src[(2*(G) + yl0)*320 + t0s*8 + c40 + 160]; \
      if(has1){ \
        pa1 = src[(2*(G) + yl1)*320 + t1s*8 + c41]; \
        pb1 = src[(2*(G) + yl1)*320 + t1s*8 + c41 + 160]; \
      } \
    } \
  }while(0)

#define TY_STAGE(BUF) do{ \
    if constexpr(LIFT){ \
      const float* wrp = wT2 + c40*24; \
      float4 w0v = *(const float4*)(wrp); \
      float4 w1v = *(const float4*)(wrp+4); \
      float4 w2v = *(const float4*)(wrp+8); \
      float4 w3v = *(const float4*)(wrp+12); \
      float4 w4v = *(const float4*)(wrp+16); \
      float4 wbv = *(const float4*)(wrp+20); \
      float su0=hA0.x+hB0.x, su1=hA0.y+hB0.y, su2=xA00+xB00, su3=xA01+xB01, su4=xA02+xB02; \
      float sd0=hA0.x-hB0.x, sd1=hA0.y-hB0.y, sd2=xA00-xB00, sd3=xA01-xB01, sd4=xA02-xB02; \
      float* bse = (BUF) + yl0*1344 + t0s; \
      _Pragma("unroll") \
      for(int e=0;e<4;e++){ \
        float w0=((float*)&w0v)[e], w1=((float*)&w1v)[e], w2=((float*)&w2v)[e]; \
        float w3=((float*)&w3v)[e], w4=((float*)&w4v)[e], wb=((float*)&wbv)[e]; \
        bse[(4*c40+e)*42]      = wb + su0*w0 + su1*w1 + su2*w2 + su3*w3 + su4*w4; \
        bse[(4*c40+e)*42 + 20] =      sd0*w0 + sd1*w1 + sd2*w2 + sd3*w3 + sd4*w4; \
      } \
      if(has1){ \
        float tu0=hA1.x+hB1.x, tu1=hA1.y+hB1.y, tu2=xA10+xB10, tu3=xA11+xB11, tu4=xA12+xB12; \
        float td0=hA1.x-hB1.x, td1=hA1.y-hB1.y, td2=xA10-xB10, td3=xA11-xB11, td4=xA12-xB12; \
        float* bs1 = (BUF) + yl1*1344 + t1s; \
        _Pragma("unroll") \
        for(int e=0;e<4;e++){ \
          float w0=((float*)&w0v)[e], w1=((float*)&w1v)[e], w2=((float*)&w2v)[e]; \
          float w3=((float*)&w3v)[e], w4=((float*)&w4v)[e], wb=((float*)&wbv)[e]; \
          bs1[(4*c41+e)*42]      = wb + tu0*w0 + tu1*w1 + tu2*w2 + tu3*w3 + tu4*w4; \
          bs1[(4*c41+e)*42 + 20] =      td0*w0 + td1*w1 + td2*w2 + td3*w3 + td4*w4; \
        } \
      } \
    } else { \
      float* bse = (BUF) + yl0*1344 + t0s; \
      _Pragma("unroll") \
      for(int e=0;e<4;e++){ \
        float av=((float*)&pa0)[e], bv=((float*)&pb0)[e]; \
        bse[(4*c40+e)*42]      = av+bv; \
        bse[(4*c40+e)*42 + 20] = av-bv; \
      } \
      if(has1){ \
        float* bs1 = (BUF) + yl1*1344 + t1s; \
        _Pragma("unroll") \
        for(int e=0;e<4;e++){ \
          float av=((float*)&pa1)[e], bv=((float*)&pb1)[e]; \
          bs1[(4*c41+e)*42]      = av+bv; \
          bs1[(4*c41+e)*42 + 20] = av-bv; \
        } \
      } \
    } \
  }while(0)

  // ---- prologue: group g=h -> myb0; prefetch group h+2 ----
  TY_LOAD(h);
  TY_STAGE(myb0);
  TY_LOAD(h+2);
  __syncthreads();                         // my buf0 + twy visible

  #pragma unroll 1
  for(int it=0; it<16; ++it){
    int g = 2*it + h;                      // h=0: even groups, h=1: odd; union = all 32
    const float* vb = (it&1) ? myb1 : myb0;
    float*       vn = (it&1) ? myb0 : myb1;
    if(it+1<16){                           // stage group g+2 (regs -> vn)
      TY_STAGE(vn);
      if(it+2<16){                         // issue loads for group g+4
        TY_LOAD(g+4);
      }
    }
    // compute the 2 y of group g
    {
      const float* vp0 = vb + c*42 + toff;
      const float* vp1 = vp0 + 1344;
      float sr0=0.f,si0=0.f,sr1=0.f,si1=0.f;
      #pragma unroll
      for(int i5=0; i5<5; i5++){
        float2 a0 = *(const float2*)(vp0 + i5*4);
        float2 b0 = *(const float2*)(vp0 + i5*4 + 2);
        float2 a1 = *(const float2*)(vp1 + i5*4);
        float2 b1 = *(const float2*)(vp1 + i5*4 + 2);
        float2 w0=twr[i5*4], w1=twr[i5*4+1], w2=twr[i5*4+2], w3=twr[i5*4+3];
        sr0 += a0.x*w0.x + a0.y*w1.x + b0.x*w2.x + b0.y*w3.x;
        si0 += a0.x*w0.y + a0.y*w1.y + b0.x*w2.y + b0.y*w3.y;
        sr1 += a1.x*w0.x + a1.y*w1.x + b1.x*w2.x + b1.y*w3.x;
        si1 += a1.x*w0.y + a1.y*w1.y + b1.x*w2.y + b1.y*w3.y;
      }
      int y = 2*g;                         // even -> float4 twy pair aligned
      #pragma unroll
      for(int q=0;q<KYC;q++){
        float4 wy = *(const float4*)&twy[q*NY + y];   // (w_y, w_{y+1}) broadcast
        acc[q].x += sr0*wy.x - si0*wy.y + sr1*wy.z - si1*wy.w;
        acc[q].y += sr0*wy.y + si0*wy.x + sr1*wy.w + si1*wy.z;
      }
    }
    barrier_lds();                         // one barrier per group-step
  }
  // epilogue merge: buffers/twy dead after final barrier -> f2out alias safe
  if(h==0){
    #pragma unroll
    for(int q=0;q<KYC;q++) f2out[c*193 + q*8 + k] = acc[q];
  }
  __syncthreads();
  if(h==1){
    #pragma unroll
    for(int q=0;q<KYC;q++){
      float2 v = f2out[c*193 + q*8 + k];
      f2out[c*193 + q*8 + k] = make_float2(v.x+acc[q].x, v.y+acc[q].y);
    }
  }
  __syncthreads();
  for(int i=tid;i<WID*KYC*KT;i+=512){
    int cc=i/192, e=i-cc*192;
    F2[((size_t)(b*WID+cc)*NX + x)*(KYC*KT) + e] = f2out[cc*193 + e];
  }
#undef TY_LOAD
#undef TY_STAGE
}

// ---------------- forward X: F2 -> F3 [B,32,24,24,8] cplx ----------------
__global__ __launch_bounds__(256) void k_fwd_x(const float2* __restrict__ F2, float2* __restrict__ F3){
  __shared__ float2 tile[NX*KT];
  __shared__ float2 twi[KXC*65];          // stride 65 cplx
  int tid=threadIdx.x;
  int bc = blockIdx.x / KYC;
  int ky = blockIdx.x - bc*KYC;
  for(int i=tid;i<NX*KT;i+=256){
    int xx=i/KT, kt=i-xx*KT;
    tile[i] = F2[((size_t)bc*NX + xx)*(KYC*KT) + ky*KT + kt];
  }
  for(int i=tid;i<KXC*NX;i+=256){
    int kx=i/NX, xx=i-kx*NX;
    int f = kx<M1C ? kx : kx+40;
    float ang = -TWO_PI*(float)((f*xx)%NX)/(float)NX;
    twi[kx*65+xx] = make_float2(cosf(ang), sinf(ang));
  }
  __syncthreads();
  for(int item=tid; item<KXC*KT; item+=256){
    int kx=item/KT, kt=item-kx*KT;
    float sr=0.f, si=0.f;
    #pragma unroll 8
    for(int xx=0;xx<NX;xx++){
      float2 a = tile[xx*KT+kt];
      float2 w = twi[kx*65+xx];
      sr += a.x*w.x - a.y*w.y;
      si += a.x*w.y + a.y*w.x;
    }
    F3[(size_t)bc*(KXC*KYC*KT) + kx*(KYC*KT) + ky*KT + kt] = make_float2(sr,si);
  }
}

// ---------------- channel mix: F3 -> F4 ----------------
__global__ __launch_bounds__(256) void k_mix(const float2* __restrict__ F3, const float* __restrict__ wr,
                                             const float* __restrict__ wi, float2* __restrict__ F4){
  __shared__ float2 f3s[BATCH*WID*KT];     // [b][i][kt] = 16 KB
  int tid = threadIdx.x;
  int kx = blockIdx.x / KYC, ky = blockIdx.x - kx*KYC;
  int mode0 = blockIdx.x * KT;
  int xp = (kx>=M1C), yp = (ky>=M1C);
  int m1 = kx - M1C*xp, m2 = ky - M1C*yp;
  int blk = xp + 2*yp;
  for(int i=tid;i<1024;i+=256){
    int row=i>>2, q=i&3;
    ((float4*)f3s)[row*4+q] = ((const float4*)(F3 + (size_t)row*4608 + mode0))[q];
  }
  int o = tid>>3, kt = tid&7;
  size_t wbase = (size_t)blk*1179648 + (size_t)o*1152 + m1*96 + m2*8 + kt;
  float wre[WID], wim[WID];
  #pragma unroll
  for(int i=0;i<WID;i++){
    wre[i] = wr[wbase + (size_t)i*36864];
    wim[i] = wi[wbase + (size_t)i*36864];
  }
  __syncthreads();
  #pragma unroll
  for(int b=0;b<BATCH;b++){
    float ar=0.f, ai=0.f;
    #pragma unroll
    for(int i=0;i<WID;i++){
      float2 a = f3s[(b*WID+i)*KT + kt];
      ar += a.x*wre[i] - a.y*wim[i];
      ai += a.x*wim[i] + a.y*wre[i];
    }
    F4[(size_t)(b*WID+o)*4608 + mode0 + kt] = make_float2(ar,ai);
  }
}

// ---------------- inverse X: F4 -> F2 (1/64 folded) ----------------
__global__ __launch_bounds__(256) void k_inv_x(const float2* __restrict__ F4, float2* __restrict__ F2){
  __shared__ float2 tile[KXC*KT];
  __shared__ float2 twi[NX*25];
  int tid=threadIdx.x;
  int bc = blockIdx.x / KYC, ky = blockIdx.x - (blockIdx.x/KYC)*KYC;
  for(int i=tid;i<KXC*KT;i+=256){
    int kx=i/KT, kt=i-kx*KT;
    tile[i] = F4[(size_t)bc*4608 + kx*(KYC*KT) + ky*KT + kt];
  }
  for(int i=tid;i<NX*KXC;i+=256){
    int xx=i/KXC, kx=i-xx*KXC;
    int f = kx<M1C ? kx : kx+40;
    float ang = TWO_PI*(float)((f*xx)%NX)/(float)NX;
    twi[xx*25+kx] = make_float2(cosf(ang)*(1.0f/64.0f), sinf(ang)*(1.0f/64.0f));
  }
  __syncthreads();
  for(int item=tid; item<NX*KT; item+=256){
    int xx=item/KT, kt=item-xx*KT;
    float sr=0.f, si=0.f;
    #pragma unroll 8
    for(int kx=0;kx<KXC;kx++){
      float2 a = tile[kx*KT+kt];
      float2 w = twi[xx*25+kx];
      sr += a.x*w.x - a.y*w.y;
      si += a.x*w.y + a.y*w.x;
    }
    F2[((size_t)bc*NX + xx)*(KYC*KT) + ky*KT + kt] = make_float2(sr,si);
  }
}

// ------- fused inv-Y + irfft-T + conv1x1 [+gelu], in-place on V -------
// grid = B*NX*2, block = (b, x, y-half). R7 schedule (proven). LIFT=true (L0):
// the conv1x1 input plane is recomputed from h/x + wT2 instead of read from V.
// No min-waves clamp (R3-R5 bug).
template<bool GELU, bool LIFT>
__global__ __launch_bounds__(256) void k_conv(const float2* __restrict__ F2, const float* __restrict__ wcv,
                                              const float* __restrict__ bcv, float* __restrict__ V,
                                              const float* __restrict__ hin, const float* __restrict__ xin,
                                              const float* __restrict__ lw, const float* __restrict__ lb){
  __shared__ __align__(16) unsigned char smem[35840];
  float*  vtA  = (float*)smem;                  // [2][1280] = 10240 B
  float*  vtB  = (float*)(smem+10240);          // [2][1280] = 10240 B
  float2* ftc0 = (float2*)(smem+20480);         // [2][256]  =  4096 B
  float2* ftc1 = (float2*)(smem+24576);         // [2][256]  =  4096 B
  float2* twy  = (float2*)(smem+28672);         // [32][24]  =  6144 B
  float*  wT2  = (float*)(smem+34816);          // [8 c4][6 i][4 e] = 768 B
  float2* f2h  = (float2*)smem;                 // prologue alias: 24576 B

  int tid=threadIdx.x;
  int b  = blockIdx.x >> 7;
  int x  = (blockIdx.x >> 1) & 63;
  int y0 = (blockIdx.x & 1) * 32;
  int cid = tid & 31, ktid = tid >> 5;   // inv-Y identity
  int oid = tid & 31, tg  = tid >> 5;    // conv identity; t = tg*5+j

  if constexpr(LIFT){
    if(tid<192){
      int c4=tid/24, rem=tid-24*c4, i=rem>>2, e=rem&3;
      wT2[tid] = (i<5)? lw[i*32 + 4*c4 + e] : lb[4*c4+e];
    }
    // visibility covered by the prologue __syncthreads below
  }

  // ---- prologue: F2 slice -> registers via LDS (two halves) ----
  float2 fr[KYC];
  #pragma unroll
  for(int half=0; half<2; half++){
    for(int i=tid;i<1536;i+=256){
      int cc=i/96, q=i-cc*96;
      ((float4*)f2h)[i] = *((const float4*)(F2 + ((size_t)(b*WID + half*16 + cc)*NX + x)*(KYC*KT)) + q);
    }
    __syncthreads();
    if((cid>>4) == half){
      const float2* fp = f2h + (cid&15)*192 + ktid;
      #pragma unroll
      for(int ky=0;ky<KYC;ky++) fr[ky] = fp[ky*8];
    }
    __syncthreads();
  }
  // fold irfft-T scale (k==0?1:2)/NT into fr (linear through inv-Y)
  {
    float ts = (ktid==0 ? 1.0f : 2.0f) * (1.0f/(float)NT);
    #pragma unroll
    for(int ky=0;ky<KYC;ky++){ fr[ky].x *= ts; fr[ky].y *= ts; }
  }
  float wreg[WID];
  #pragma unroll
  for(int cc=0;cc<WID;cc++) wreg[cc] = wcv[oid*WID + cc];
  float breg = bcv[oid];
  // per-thread T-twiddle base: e^{i*pi/4*(k*tg mod 8)}  (t = 5*tg + j)
  float2 twtg[KT];
  #pragma unroll
  for(int k=0;k<KT;k++){
    float ang = 0.78539816339744831f*(float)((k*tg)&7);
    twtg[k] = make_float2(cosf(ang), sinf(ang));
  }
  for(int i=tid;i<32*KYC;i+=256){
    int yy=i/KYC, ky=i-yy*KYC;
    int f = ky<M1C ? ky : ky+40;
    float ang = TWO_PI*(float)((f*(y0+yy))%NY)/(float)NY;
    twy[i] = make_float2(cosf(ang)*(1.0f/64.0f), sinf(ang)*(1.0f/64.0f));
  }
  float* plane = V + (size_t)((b*NX+x)*NY + y0)*(NT*WID);
  const float4* gp = (const float4*)plane;
  const float* hbc = hin + (size_t)((b*NX+x)*NY + y0)*NT*2;
  const float* xbc = xin + (size_t)((b*NX+x)*NY + y0)*NT*3;
  bool has3 = tid < 128;
  // slot decomposition for LIFT staging: 640 f4-slots = [yy 2][t 40][c4 8]
  int t0c = tid>>3;                        // slot tid      (yy=0)
  int yy1c = (tid>=64);                    // slot tid+256
  int t1c = yy1c ? ((tid-64)>>3) : ((tid+256)>>3);
  int t2c = (tid+192)>>3;                  // slot tid+512  (yy=1, tid<128)
  int c4c = tid&7;                         // same c4 for all three slots

  float4 rA, rB, rC;                       // non-LIFT prefetch
  float2 hC0, hC1, hC2;                    // LIFT prefetch
  float xC00,xC01,xC02,xC10,xC11,xC12,xC20,xC21,xC22;

#define CV_LOAD(P) do{ \
    if constexpr(LIFT){ \
      { size_t pt = (size_t)((2*(P))*40 + t0c); \
        hC0 = *(const float2*)(hbc + pt*2); \
        xC00 = xbc[pt*3]; xC01 = xbc[pt*3+1]; xC02 = xbc[pt*3+2]; } \
      { size_t pt = (size_t)((2*(P)+yy1c)*40 + t1c); \
        hC1 = *(const float2*)(hbc + pt*2); \
        xC10 = xbc[pt*3]; xC11 = xbc[pt*3+1]; xC12 = xbc[pt*3+2]; } \
      if(has3){ size_t pt = (size_t)((2*(P)+1)*40 + t2c); \
        hC2 = *(const float2*)(hbc + pt*2); \
        xC20 = xbc[pt*3]; xC21 = xbc[pt*3+1]; xC22 = xbc[pt*3+2]; } \
    } else { \
      const float4* q = gp + (size_t)(P)*640; \
      rA = q[tid]; rB = q[256+tid]; \
      if(has3) rC = q[512+tid]; \
    } \
  }while(0)

#define CV_STAGE(BUF) do{ \
    if constexpr(LIFT){ \
      const float* wrp = wT2 + c4c*24; \
      float4 w0v = *(const float4*)(wrp); \
      float4 w1v = *(const float4*)(wrp+4); \
      float4 w2v = *(const float4*)(wrp+8); \
      float4 w3v = *(const float4*)(wrp+12); \
      float4 w4v = *(const float4*)(wrp+16); \
      float4 wbv = *(const float4*)(wrp+20); \
      float4 v0, v1, v2; \
      _Pragma("unroll") \
      for(int e=0;e<4;e++){ \
        float w0=((float*)&w0v)[e], w1=((float*)&w1v)[e], w2=((float*)&w2v)[e]; \
        float w3=((float*)&w3v)[e], w4=((float*)&w4v)[e], wb=((float*)&wbv)[e]; \
        ((float*)&v0)[e] = wb + hC0.x*w0 + hC0.y*w1 + xC00*w2 + xC01*w3 + xC02*w4; \
        ((float*)&v1)[e] = wb + hC1.x*w0 + hC1.y*w1 + xC10*w2 + xC11*w3 + xC12*w4; \
        if(has3) ((float*)&v2)[e] = wb + hC2.x*w0 + hC2.y*w1 + xC20*w2 + xC21*w3 + xC22*w4; \
      } \
      ((float4*)(BUF))[tid] = v0; \
      ((float4*)(BUF))[256+tid] = v1; \
      if(has3) ((float4*)(BUF))[512+tid] = v2; \
    } else { \
      ((float4*)(BUF))[tid] = rA; \
      ((float4*)(BUF))[256+tid] = rB; \
      if(has3) ((float4*)(BUF))[512+tid] = rC; \
    } \
  }while(0)

  // stage pair 0 into vtA; prefetch pair 1 into regs
  CV_LOAD(0);
  CV_STAGE(vtA);
  CV_LOAD(1);
  __syncthreads();                        // publish vtA + twy (+wT2) (prologue only)

  // cos/sin(pi*k*j/20) — compile-time literals (fold into v_fmac immediates)
  constexpr float CJ[KT][5] = {
    {1.f, 1.f,          1.f,          1.f,          1.f         },
    {1.f, 0.98768834f,  0.95105652f,  0.89100652f,  0.80901699f },
    {1.f, 0.95105652f,  0.80901699f,  0.58778525f,  0.30901699f },
    {1.f, 0.89100652f,  0.58778525f,  0.15643447f, -0.30901699f },
    {1.f, 0.80901699f,  0.30901699f, -0.30901699f, -0.80901699f },
    {1.f, 0.70710678f,  0.f,         -0.70710678f, -1.f         },
    {1.f, 0.58778525f, -0.30901699f, -0.95105652f, -0.80901699f },
    {1.f, 0.45399050f, -0.58778525f, -0.98768834f, -0.30901699f },
  };
  constexpr float SJ[KT][5] = {
    {0.f, 0.f,          0.f,          0.f,          0.f         },
    {0.f, 0.15643447f,  0.30901699f,  0.45399050f,  0.58778525f },
    {0.f, 0.30901699f,  0.58778525f,  0.80901699f,  0.95105652f },
    {0.f, 0.45399050f,  0.80901699f,  0.98768834f,  0.95105652f },
    {0.f, 0.58778525f,  0.95105652f,  0.95105652f,  0.58778525f },
    {0.f, 0.70710678f,  1.f,          0.70710678f,  0.f         },
    {0.f, 0.80901699f,  0.95105652f,  0.30901699f, -0.58778525f },
    {0.f, 0.89100652f,  0.80901699f, -0.15643447f, -0.95105652f },
  };

  #pragma unroll 1
  for(int it=0; it<16; ++it){
    float*  vcur = (it&1) ? vtB  : vtA;
    float*  vnxt = (it&1) ? vtA  : vtB;
    float2* fcur = (it&1) ? ftc1 : ftc0;
    int yl = it*2;
    { // inverse-Y for y=yl and yl+1, interleaved chains, b128 ky-pair twiddles
      const float2* tw0 = twy + (size_t)yl*KYC;
      const float2* tw1 = tw0 + KYC;
      float sr0=0.f, si0=0.f, sr1=0.f, si1=0.f;
      #pragma unroll
      for(int ky=0;ky<KYC;ky+=2){
        float2 a  = fr[ky];
        float2 b2 = fr[ky+1];
        float4 w0 = *(const float4*)&tw0[ky];
        float4 w1 = *(const float4*)&tw1[ky];
        sr0 += a.x*w0.x - a.y*w0.y + b2.x*w0.z - b2.y*w0.w;
        si0 += a.x*w0.y + a.y*w0.x + b2.x*w0.w + b2.y*w0.z;
        sr1 += a.x*w1.x - a.y*w1.y + b2.x*w1.z - b2.y*w1.w;
        si1 += a.x*w1.y + a.y*w1.x + b2.x*w1.w + b2.y*w1.z;
      }
      fcur[      ktid*32 + cid] = make_float2(sr0,si0);
      fcur[256 + ktid*32 + cid] = make_float2(sr1,si1);
    }
    barrier_lds();                        // the ONLY barrier per iteration
    // stage pair it+1 (regs -> vnxt) BEFORE this iteration's stores
    if(it+1 < 16){
      CV_STAGE(vnxt);
    }
    if(it+2 < 16){                        // issue loads for pair it+2
      CV_LOAD(it+2);
    }
    #pragma unroll
    for(int yy=0; yy<2; yy++){            // conv1x1 + irfft-T for the two y
      const float2* fsrc = fcur + yy*256;
      const float*  vb   = vcur + yy*1280;
      float* outp = plane + (size_t)(yl+yy)*(NT*WID);
      float acc[5];
      #pragma unroll
      for(int j=0;j<5;j++) acc[j] = breg;
      #pragma unroll
      for(int k=0;k<KT;k++){              // rotate mode by twtg, then literal DFT
        float2 f = fsrc[k*32 + oid];
        float gx = f.x*twtg[k].x - f.y*twtg[k].y;
        float gy = f.x*twtg[k].y + f.y*twtg[k].x;
        #pragma unroll
        for(int j=0;j<5;j++) acc[j] += gx*CJ[k][j] - gy*SJ[k][j];
      }
      #pragma unroll
      for(int j=0;j<5;j++){
        int t = tg*5 + j;
        float a = acc[j];
        const float* vrow = vb + t*32;
        #pragma unroll
        for(int c4=0;c4<WID;c4+=4){
          float4 vv = *(const float4*)(vrow + c4);   // broadcast b128
          a += vv.x*wreg[c4] + vv.y*wreg[c4+1] + vv.z*wreg[c4+2] + vv.w*wreg[c4+3];
        }
        outp[t*32 + oid] = GELU ? gelu_f(a) : a;     // lanes 0-31: one full 128B line
      }
    }
  }
#undef CV_LOAD
#undef CV_STAGE
}

// ---------------- fused fc1+gelu+fc2: V -> out [B,X,Y,T,2] ----------------
__global__ __launch_bounds__(256) void k_mlp(const float* __restrict__ V, const float* __restrict__ w1,
                                             const float* __restrict__ b1, const float* __restrict__ w2,
                                             const float* __restrict__ b2, float* __restrict__ out){
  __shared__ float sw1t[64*WID];          // [j][c]
  __shared__ float sb1[64], sw2[128], sb2[2];
  int tid=threadIdx.x;
  for(int i=tid;i<64*WID;i+=256){ int j=i>>5, c=i&31; sw1t[i]=w1[c*64+j]; }
  if(tid<64) sb1[tid]=b1[tid];
  if(tid<128) sw2[tid]=w2[tid];
  if(tid<2) sb2[tid]=b2[tid];
  __syncthreads();
  size_t p0 = (size_t)blockIdx.x*1024 + (size_t)tid*4;
  float vv[128];
  const float4* vp = (const float4*)(V + p0*WID);
  #pragma unroll
  for(int q=0;q<32;q++) *((float4*)(vv+4*q)) = vp[q];
  float oa[8];
  #pragma unroll
  for(int pt=0;pt<4;pt++){ oa[2*pt]=sb2[0]; oa[2*pt+1]=sb2[1]; }
  #pragma unroll 4
  for(int j=0;j<64;j++){
    float a0=sb1[j], a1=a0, a2=a0, a3=a0;
    const float* wrow = sw1t + j*WID;
    #pragma unroll
    for(int c4=0;c4<WID;c4+=4){
      float4 w = *(const float4*)(wrow + c4);        // broadcast b128
      a0 += vv[     c4]*w.x + vv[     c4+1]*w.y + vv[     c4+2]*w.z + vv[     c4+3]*w.w;
      a1 += vv[32 + c4]*w.x + vv[32 + c4+1]*w.y + vv[32 + c4+2]*w.z + vv[32 + c4+3]*w.w;
      a2 += vv[64 + c4]*w.x + vv[64 + c4+1]*w.y + vv[64 + c4+2]*w.z + vv[64 + c4+3]*w.w;
      a3 += vv[96 + c4]*w.x + vv[96 + c4+1]*w.y + vv[96 + c4+2]*w.z + vv[96 + c4+3]*w.w;
    }
    a0=gelu_f(a0); a1=gelu_f(a1); a2=gelu_f(a2); a3=gelu_f(a3);
    float u0=sw2[2*j], u1=sw2[2*j+1];
    oa[0]+=a0*u0; oa[1]+=a0*u1; oa[2]+=a1*u0; oa[3]+=a1*u1;
    oa[4]+=a2*u0; oa[5]+=a2*u1; oa[6]+=a3*u0; oa[7]+=a3*u1;
  }
  float4* op = (float4*)(out + p0*2);
  op[0]=make_float4(oa[0],oa[1],oa[2],oa[3]);
  op[1]=make_float4(oa[4],oa[5],oa[6],oa[7]);
}

extern "C" void kernel_launch(void* const* d_in, const int* in_sizes, int n_in,
                              void* d_out, int out_size, void* d_ws, size_t ws_size,
                              hipStream_t stream){
  const float* h     = (const float*)d_in[0];
  const float* x     = (const float*)d_in[1];
  const float* fc0_w = (const float*)d_in[2];
  const float* fc0_b = (const float*)d_in[3];
  const float* scwr[3] = {(const float*)d_in[4], (const float*)d_in[6], (const float*)d_in[8]};
  const float* scwi[3] = {(const float*)d_in[5], (const float*)d_in[7], (const float*)d_in[9]};
  const float* cw[3]   = {(const float*)d_in[10], (const float*)d_in[12], (const float*)d_in[14]};
  const float* cb[3]   = {(const float*)d_in[11], (const float*)d_in[13], (const float*)d_in[15]};
  const float* fc1_w = (const float*)d_in[16];
  const float* fc1_b = (const float*)d_in[17];
  const float* fc2_w = (const float*)d_in[18];
  const float* fc2_b = (const float*)d_in[19];

  // workspace: V (167.8 MB, layout [b,x,y,t,c]) | F2 (25.2 MB) | F4 (9.4 MB)
  // F3 lives in d_out (9.4 MB <= 10.5 MB) until k_mlp overwrites it.
  // R11: V is first written by k_conv L0 (fc0 lift fused into L0 consumers).
  const size_t VSZ = (size_t)BATCH*WID*NXYT;
  float*  V  = (float*)d_ws;
  float2* F2 = (float2*)(V + VSZ);
  float2* F4 = F2 + (size_t)BATCH*WID*NX*KYC*KT;
  float2* F3 = (float2*)d_out;

  for(int L=0; L<3; L++){
    if(L==0) k_fwd_ty<true ><<<BATCH*NX, 512, 0, stream>>>(V, F2, h, x, fc0_w, fc0_b);
    else     k_fwd_ty<false><<<BATCH*NX, 512, 0, stream>>>(V, F2, h, x, fc0_w, fc0_b);
    k_fwd_x<<<(BATCH*WID)*KYC, 256, 0, stream>>>(F2, F3);
    k_mix<<<KXC*KYC, 256, 0, stream>>>(F3, scwr[L], scwi[L], F4);
    k_inv_x<<<(BATCH*WID)*KYC, 256, 0, stream>>>(F4, F2);
    if(L==0)      k_conv<true ,true ><<<BATCH*NX*2, 256, 0, stream>>>(F2, cw[0], cb[0], V, h, x, fc0_w, fc0_b);
    else if(L==1) k_conv<true ,false><<<BATCH*NX*2, 256, 0, stream>>>(F2, cw[1], cb[1], V, h, x, fc0_w, fc0_b);
    else          k_conv<false,false><<<BATCH*NX*2, 256, 0, stream>>>(F2, cw[2], cb[2], V, h, x, fc0_w, fc0_b);
  }
  k_mlp<<<NP/1024, 256, 0, stream>>>(V, fc1_w, fc1_b, fc2_w, fc2_b, (float*)d_out);
}

// Round 8
// 1300.438 us; speedup vs baseline: 1.0960x; 1.0557x over previous
//
#include <hip/hip_runtime.h>
#include <math.h>

#define BATCH 8
#define WID   32
#define NX    64
#define NY    64
#define NT    40
#define M1C   12
#define KT    8      // M3
#define KXC   24
#define KYC   24
#define NXY   (NX*NY)        // 4096
#define NXYT  (NXY*NT)       // 163840
#define NP    (BATCH*NXYT)   // 1310720

#define TWO_PI 6.283185307179586f

static __device__ __forceinline__ float gelu_f(float v){
  return 0.5f*v*(1.0f + erff(v*0.7071067811865476f));
}

// barrier that does NOT drain vmcnt (keeps global prefetch loads in flight).
static __device__ __forceinline__ void barrier_lds(){
  asm volatile("s_waitcnt lgkmcnt(0)\n\ts_barrier" ::: "memory");
}

// V layout throughout: [b][x][y][t][c]  (channel-innermost, plane = 1280 floats)
// R11: k_fc0 DELETED — lift recomputed inline by the L0 consumers.
// R12: lift table wT2[c4][6][e] (2-way banks; R11's wTl[c][8] was 8-way).
// R13: fwd_ty Y-radix-2. f(ky) parity == ky parity, so w64^{f(y+32)} =
//   (-1)^ky w64^{fy}: stage 4 planes (y,y+32 x t,t+20) butterflied into 4
//   parity quadrants B[py][pt]; T-DFT cost unchanged (linear), mode-accum
//   HALVES (192->96 fma per 2y), y-twiddle table halves ([24][32]).
//   256-thr block again (R10 h-split was occupancy-neutral).

// ------- fused forward T+Y per (b,x): V slice -> F2 [bc*64+x][ky*8+kt] -------
template<bool LIFT>
__global__ __launch_bounds__(256) void k_fwd_ty(const float* __restrict__ V, float2* __restrict__ F2,
                                                const float* __restrict__ hin, const float* __restrict__ xin,
                                                const float* __restrict__ lw, const float* __restrict__ lb){
  __shared__ __align__(16) unsigned char smem[49920];
  // buf[p] at p*21504: [yl 2][py 2][32 c][42] floats (pt packed in 42-pitch)
  float2* twy2  = (float2*)(smem+43008);        // [24 q][32 y] = 6144 B
  float*  wT2   = (float*)(smem+49152);         // [8 c4][6 i][4 e] = 768 B
  float2* f2out = (float2*)smem;                // epilogue alias: 32*193*8 = 49408 B
  int tid = threadIdx.x;
  int b = blockIdx.x >> 6, x = blockIdx.x & 63;
  int c = tid & 31, k = tid >> 5;
  if constexpr(LIFT){
    if(tid<192){
      int c4=tid/24, rem=tid-24*c4, i=rem>>2, e=rem&3;
      wT2[tid] = (i<5)? lw[i*32 + 4*c4 + e] : 4.0f*lb[4*c4+e];   // 4x bias: UU quadrant
    }
    __syncthreads();                     // wT2 visible before first staging
  }
  for(int i=tid;i<KYC*32;i+=256){
    int q=i>>5, y=i&31;
    int f = q<M1C ? q : q+40;
    float ang = -TWO_PI*(float)((f*y)%NY)/(float)NY;
    twy2[i] = make_float2(cosf(ang), sinf(ang));
  }
  // per-thread T-twiddle HALF-row (T-radix-2)
  float2 twr[20];
  #pragma unroll
  for(int t=0;t<20;t++){
    float ang = -TWO_PI*(float)((k*t)%NT)/(float)NT;
    twr[t] = make_float2(cosf(ang), sinf(ang));
  }
  int toff = (k&1)*20;                     // even k -> T+ half, odd k -> T- half
  float2 acc[KYC];
  #pragma unroll
  for(int q=0;q<KYC;q++) acc[q]=make_float2(0.f,0.f);
  const float4* src = (const float4*)(V + (size_t)(b*NX+x)*(NY*NT*WID));
  const float* hb = hin + (size_t)(b*NX+x)*(NY*NT)*2;
  const float* xb = xin + (size_t)(b*NX+x)*(NY*NT)*3;
  float* bf0 = (float*)smem;
  float* bf1 = bf0 + 5376;                 // +21504 B

  // staging slots for a 4-plane group g (y=2g,2g+1,2g+32,2g+33):
  // s in [0,320) = [yl 2][t 20][c4 8]; 4 loads (y/y+32 x t/t+20) -> 4 quadrants.
  int s0 = tid;
  int c40 = s0&7, t0s = (s0>>3)%20, yl0 = s0/160;
  bool has1 = (tid < 64);
  int t1s = ((tid>>3)+12);                 // ((tid+256)>>3)%20, tid<64
  // yl1 = 1 always; c41 == c40

  float4 pa0,pb0,pc0,pd0, pa1,pb1,pc1,pd1;          // non-LIFT prefetch (v1..v4 x 2 slots)
  float2 h10,h20,h30,h40, h11,h21,h31,h41;          // LIFT prefetch
  float x10[3],x20[3],x30[3],x40[3], x11[3],x21[3],x31[3],x41[3];

#define TY_LOAD(G) do{ \
    if constexpr(LIFT){ \
      { int p = (2*(G)+yl0)*40 + t0s; \
        h10 = *(const float2*)(hb + (size_t)p*2);        h20 = *(const float2*)(hb + (size_t)(p+20)*2); \
        h30 = *(const float2*)(hb + (size_t)(p+1280)*2); h40 = *(const float2*)(hb + (size_t)(p+1300)*2); \
        for(int ii=0;ii<3;ii++){ x10[ii]=xb[(size_t)p*3+ii]; x20[ii]=xb[(size_t)(p+20)*3+ii]; \
                                 x30[ii]=xb[(size_t)(p+1280)*3+ii]; x40[ii]=xb[(size_t)(p+1300)*3+ii]; } } \
      if(has1){ int p = (2*(G)+1)*40 + t1s; \
        h11 = *(const float2*)(hb + (size_t)p*2);        h21 = *(const float2*)(hb + (size_t)(p+20)*2); \
        h31 = *(const float2*)(hb + (size_t)(p+1280)*2); h41 = *(const float2*)(hb + (size_t)(p+1300)*2); \
        for(int ii=0;ii<3;ii++){ x11[ii]=xb[(size_t)p*3+ii]; x21[ii]=xb[(size_t)(p+20)*3+ii]; \
                                 x31[ii]=xb[(size_t)(p+1280)*3+ii]; x41[ii]=xb[(size_t)(p+1300)*3+ii]; } } \
    } else { \
      { const float4* q0 = src + (size_t)(2*(G)+yl0)*320 + t0s*8 + c40; \
        pa0 = q0[0]; pb0 = q0[160]; pc0 = q0[10240]; pd0 = q0[10400]; } \
      if(has1){ const float4* q1 = src + (size_t)(2*(G)+1)*320 + t1s*8 + c40; \
        pa1 = q1[0]; pb1 = q1[160]; pc1 = q1[10240]; pd1 = q1[10400]; } \
    } \
  }while(0)

#define TY_BFLY_STORE(BUF, YL, TS, C4, A1, A2, A3, A4) do{ \
    _Pragma("unroll") \
    for(int e=0;e<4;e++){ \
      float a1=((float*)&A1)[e], a2=((float*)&A2)[e], a3=((float*)&A3)[e], a4=((float*)&A4)[e]; \
      float u13=a1+a3, d13=a1-a3, u24=a2+a4, d24=a2-a4; \
      float* bse = (BUF) + (YL)*2688 + (4*(C4)+e)*42 + (TS); \
      bse[0]    = u13+u24;  /* py0 pt0 */ \
      bse[20]   = u13-u24;  /* py0 pt1 */ \
      bse[1344] = d13+d24;  /* py1 pt0 */ \
      bse[1364] = d13-d24;  /* py1 pt1 */ \
    } \
  }while(0)

#define TY_LIFT_STORE(BUF, YL, TS, C4, H1, H2, H3, H4, X1, X2, X3, X4) do{ \
    float s00[5], s01[5], s10[5], s11[5]; \
    { float a=H1.x,b2=H2.x,c2=H3.x,d2=H4.x; s00[0]=(a+b2)+(c2+d2); s01[0]=(a-b2)+(c2-d2); s10[0]=(a+b2)-(c2+d2); s11[0]=(a-b2)-(c2-d2); } \
    { float a=H1.y,b2=H2.y,c2=H3.y,d2=H4.y; s00[1]=(a+b2)+(c2+d2); s01[1]=(a-b2)+(c2-d2); s10[1]=(a+b2)-(c2+d2); s11[1]=(a-b2)-(c2-d2); } \
    _Pragma("unroll") \
    for(int ii=0;ii<3;ii++){ float a=X1[ii],b2=X2[ii],c2=X3[ii],d2=X4[ii]; \
      s00[2+ii]=(a+b2)+(c2+d2); s01[2+ii]=(a-b2)+(c2-d2); s10[2+ii]=(a+b2)-(c2+d2); s11[2+ii]=(a-b2)-(c2-d2); } \
    const float* wrp = wT2 + (C4)*24; \
    float4 w0v = *(const float4*)(wrp); \
    float4 w1v = *(const float4*)(wrp+4); \
    float4 w2v = *(const float4*)(wrp+8); \
    float4 w3v = *(const float4*)(wrp+12); \
    float4 w4v = *(const float4*)(wrp+16); \
    float4 wbv = *(const float4*)(wrp+20); \
    _Pragma("unroll") \
    for(int e=0;e<4;e++){ \
      float w0=((float*)&w0v)[e], w1=((float*)&w1v)[e], w2=((float*)&w2v)[e]; \
      float w3=((float*)&w3v)[e], w4=((float*)&w4v)[e], wb=((float*)&wbv)[e]; \
      float* bse = (BUF) + (YL)*2688 + (4*(C4)+e)*42 + (TS); \
      bse[0]    = wb + s00[0]*w0 + s00[1]*w1 + s00[2]*w2 + s00[3]*w3 + s00[4]*w4; \
      bse[20]   =      s01[0]*w0 + s01[1]*w1 + s01[2]*w2 + s01[3]*w3 + s01[4]*w4; \
      bse[1344] =      s10[0]*w0 + s10[1]*w1 + s10[2]*w2 + s10[3]*w3 + s10[4]*w4; \
      bse[1364] =      s11[0]*w0 + s11[1]*w1 + s11[2]*w2 + s11[3]*w3 + s11[4]*w4; \
    } \
  }while(0)

#define TY_STAGE(BUF) do{ \
    if constexpr(LIFT){ \
      TY_LIFT_STORE(BUF, yl0, t0s, c40, h10, h20, h30, h40, x10, x20, x30, x40); \
      if(has1) TY_LIFT_STORE(BUF, 1, t1s, c40, h11, h21, h31, h41, x11, x21, x31, x41); \
    } else { \
      TY_BFLY_STORE(BUF, yl0, t0s, c40, pa0, pb0, pc0, pd0); \
      if(has1) TY_BFLY_STORE(BUF, 1, t1s, c40, pa1, pb1, pc1, pd1); \
    } \
  }while(0)

  // ---- prologue: group 0 -> bf0; prefetch group 1 ----
  TY_LOAD(0);
  TY_STAGE(bf0);
  TY_LOAD(1);
  __syncthreads();                         // bf0 + twy2 visible

  #pragma unroll 1
  for(int g=0; g<16; ++g){
    const float* vb = (g&1) ? bf1 : bf0;
    float*       vn = (g&1) ? bf0 : bf1;
    if(g+1<16){                            // stage group g+1 (regs -> vn)
      TY_STAGE(vn);
      if(g+2<16) TY_LOAD(g+2);             // issue loads for group g+2
    }
    // compute group g: 2 y-pairs (yl=0,1), U and D DFTs each
    {
      const float* p0 = vb + c*42 + toff;
      float sru0=0.f,siu0=0.f,srd0=0.f,sid0=0.f;
      float sru1=0.f,siu1=0.f,srd1=0.f,sid1=0.f;
      #pragma unroll
      for(int i5=0; i5<5; i5++){
        float2 au0 = *(const float2*)(p0 + i5*4);
        float2 bu0 = *(const float2*)(p0 + i5*4 + 2);
        float2 ad0 = *(const float2*)(p0 + 1344 + i5*4);
        float2 bd0 = *(const float2*)(p0 + 1344 + i5*4 + 2);
        float2 au1 = *(const float2*)(p0 + 2688 + i5*4);
        float2 bu1 = *(const float2*)(p0 + 2688 + i5*4 + 2);
        float2 ad1 = *(const float2*)(p0 + 4032 + i5*4);
        float2 bd1 = *(const float2*)(p0 + 4032 + i5*4 + 2);
        float2 w0=twr[i5*4], w1=twr[i5*4+1], w2=twr[i5*4+2], w3=twr[i5*4+3];
        sru0 += au0.x*w0.x + au0.y*w1.x + bu0.x*w2.x + bu0.y*w3.x;
        siu0 += au0.x*w0.y + au0.y*w1.y + bu0.x*w2.y + bu0.y*w3.y;
        srd0 += ad0.x*w0.x + ad0.y*w1.x + bd0.x*w2.x + bd0.y*w3.x;
        sid0 += ad0.x*w0.y + ad0.y*w1.y + bd0.x*w2.y + bd0.y*w3.y;
        sru1 += au1.x*w0.x + au1.y*w1.x + bu1.x*w2.x + bu1.y*w3.x;
        siu1 += au1.x*w0.y + au1.y*w1.y + bu1.x*w2.y + bu1.y*w3.y;
        srd1 += ad1.x*w0.x + ad1.y*w1.x + bd1.x*w2.x + bd1.y*w3.x;
        sid1 += ad1.x*w0.y + ad1.y*w1.y + bd1.x*w2.y + bd1.y*w3.y;
      }
      // mode accumulation: even q <- U, odd q <- D (parity(f)==parity(q))
      const float4* twp = (const float4*)&twy2[2*g];   // [q][32]: q*16 float4s
      #pragma unroll
      for(int q=0;q<KYC;q++){
        float4 w = twp[q*16];                          // (w[y=2g], w[2g+1])
        float sr0 = (q&1)? srd0 : sru0;
        float si0 = (q&1)? sid0 : siu0;
        float sr1 = (q&1)? srd1 : sru1;
        float si1 = (q&1)? sid1 : siu1;
        acc[q].x += sr0*w.x - si0*w.y + sr1*w.z - si1*w.w;
        acc[q].y += sr0*w.y + si0*w.x + sr1*w.w + si1*w.z;
      }
    }
    barrier_lds();                         // one barrier per group
  }
  // epilogue: buffers/twy2/wT2 dead after final barrier -> f2out alias safe
  #pragma unroll
  for(int q=0;q<KYC;q++) f2out[c*193 + q*8 + k] = acc[q];
  __syncthreads();
  for(int i=tid;i<WID*KYC*KT;i+=256){
    int cc=i/192, e=i-cc*192;
    F2[((size_t)(b*WID+cc)*NX + x)*(KYC*KT) + e] = f2out[cc*193 + e];
  }
#undef TY_LOAD
#undef TY_BFLY_STORE
#undef TY_LIFT_STORE
#undef TY_STAGE
}

// ---------------- forward X: F2 -> F3 [B,32,24,24,8] cplx ----------------
__global__ __launch_bounds__(256) void k_fwd_x(const float2* __restrict__ F2, float2* __restrict__ F3){
  __shared__ float2 tile[NX*KT];
  __shared__ float2 twi[KXC*65];          // stride 65 cplx
  int tid=threadIdx.x;
  int bc = blockIdx.x / KYC;
  int ky = blockIdx.x - bc*KYC;
  for(int i=tid;i<NX*KT;i+=256){
    int xx=i/KT, kt=i-xx*KT;
    tile[i] = F2[((size_t)bc*NX + xx)*(KYC*KT) + ky*KT + kt];
  }
  for(int i=tid;i<KXC*NX;i+=256){
    int kx=i/NX, xx=i-kx*NX;
    int f = kx<M1C ? kx : kx+40;
    float ang = -TWO_PI*(float)((f*xx)%NX)/(float)NX;
    twi[kx*65+xx] = make_float2(cosf(ang), sinf(ang));
  }
  __syncthreads();
  for(int item=tid; item<KXC*KT; item+=256){
    int kx=item/KT, kt=item-kx*KT;
    float sr=0.f, si=0.f;
    #pragma unroll 8
    for(int xx=0;xx<NX;xx++){
      float2 a = tile[xx*KT+kt];
      float2 w = twi[kx*65+xx];
      sr += a.x*w.x - a.y*w.y;
      si += a.x*w.y + a.y*w.x;
    }
    F3[(size_t)bc*(KXC*KYC*KT) + kx*(KYC*KT) + ky*KT + kt] = make_float2(sr,si);
  }
}

// ---------------- channel mix: F3 -> F4 ----------------
__global__ __launch_bounds__(256) void k_mix(const float2* __restrict__ F3, const float* __restrict__ wr,
                                             const float* __restrict__ wi, float2* __restrict__ F4){
  __shared__ float2 f3s[BATCH*WID*KT];     // [b][i][kt] = 16 KB
  int tid = threadIdx.x;
  int kx = blockIdx.x / KYC, ky = blockIdx.x - kx*KYC;
  int mode0 = blockIdx.x * KT;
  int xp = (kx>=M1C), yp = (ky>=M1C);
  int m1 = kx - M1C*xp, m2 = ky - M1C*yp;
  int blk = xp + 2*yp;
  for(int i=tid;i<1024;i+=256){
    int row=i>>2, q=i&3;
    ((float4*)f3s)[row*4+q] = ((const float4*)(F3 + (size_t)row*4608 + mode0))[q];
  }
  int o = tid>>3, kt = tid&7;
  size_t wbase = (size_t)blk*1179648 + (size_t)o*1152 + m1*96 + m2*8 + kt;
  float wre[WID], wim[WID];
  #pragma unroll
  for(int i=0;i<WID;i++){
    wre[i] = wr[wbase + (size_t)i*36864];
    wim[i] = wi[wbase + (size_t)i*36864];
  }
  __syncthreads();
  #pragma unroll
  for(int b=0;b<BATCH;b++){
    float ar=0.f, ai=0.f;
    #pragma unroll
    for(int i=0;i<WID;i++){
      float2 a = f3s[(b*WID+i)*KT + kt];
      ar += a.x*wre[i] - a.y*wim[i];
      ai += a.x*wim[i] + a.y*wre[i];
    }
    F4[(size_t)(b*WID+o)*4608 + mode0 + kt] = make_float2(ar,ai);
  }
}

// ---------------- inverse X: F4 -> F2 (1/64 folded) ----------------
__global__ __launch_bounds__(256) void k_inv_x(const float2* __restrict__ F4, float2* __restrict__ F2){
  __shared__ float2 tile[KXC*KT];
  __shared__ float2 twi[NX*25];
  int tid=threadIdx.x;
  int bc = blockIdx.x / KYC, ky = blockIdx.x - (blockIdx.x/KYC)*KYC;
  for(int i=tid;i<KXC*KT;i+=256){
    int kx=i/KT, kt=i-kx*KT;
    tile[i] = F4[(size_t)bc*4608 + kx*(KYC*KT) + ky*KT + kt];
  }
  for(int i=tid;i<NX*KXC;i+=256){
    int xx=i/KXC, kx=i-xx*KXC;
    int f = kx<M1C ? kx : kx+40;
    float ang = TWO_PI*(float)((f*xx)%NX)/(float)NX;
    twi[xx*25+kx] = make_float2(cosf(ang)*(1.0f/64.0f), sinf(ang)*(1.0f/64.0f));
  }
  __syncthreads();
  for(int item=tid; item<NX*KT; item+=256){
    int xx=item/KT, kt=item-xx*KT;
    float sr=0.f, si=0.f;
    #pragma unroll 8
    for(int kx=0;kx<KXC;kx++){
      float2 a = tile[kx*KT+kt];
      float2 w = twi[xx*25+kx];
      sr += a.x*w.x - a.y*w.y;
      si += a.x*w.y + a.y*w.x;
    }
    F2[((size_t)bc*NX + xx)*(KYC*KT) + ky*KT + kt] = make_float2(sr,si);
  }
}

// ------- fused inv-Y + irfft-T + conv1x1 [+gelu], in-place on V -------
// grid = B*NX*2, block = (b, x, y-half). R7 schedule (proven). LIFT=true (L0):
// the conv1x1 input plane is recomputed from h/x + wT2 instead of read from V.
// No min-waves clamp (R3-R5 bug).
template<bool GELU, bool LIFT>
__global__ __launch_bounds__(256) void k_conv(const float2* __restrict__ F2, const float* __restrict__ wcv,
                                              const float* __restrict__ bcv, float* __restrict__ V,
                                              const float* __restrict__ hin, const float* __restrict__ xin,
                                              const float* __restrict__ lw, const float* __restrict__ lb){
  __shared__ __align__(16) unsigned char smem[35840];
  float*  vtA  = (float*)smem;                  // [2][1280] = 10240 B
  float*  vtB  = (float*)(smem+10240);          // [2][1280] = 10240 B
  float2* ftc0 = (float2*)(smem+20480);         // [2][256]  =  4096 B
  float2* ftc1 = (float2*)(smem+24576);         // [2][256]  =  4096 B
  float2* twy  = (float2*)(smem+28672);         // [32][24]  =  6144 B
  float*  wT2  = (float*)(smem+34816);          // [8 c4][6 i][4 e] = 768 B
  float2* f2h  = (float2*)smem;                 // prologue alias: 24576 B

  int tid=threadIdx.x;
  int b  = blockIdx.x >> 7;
  int x  = (blockIdx.x >> 1) & 63;
  int y0 = (blockIdx.x & 1) * 32;
  int cid = tid & 31, ktid = tid >> 5;   // inv-Y identity
  int oid = tid & 31, tg  = tid >> 5;    // conv identity; t = tg*5+j

  if constexpr(LIFT){
    if(tid<192){
      int c4=tid/24, rem=tid-24*c4, i=rem>>2, e=rem&3;
      wT2[tid] = (i<5)? lw[i*32 + 4*c4 + e] : lb[4*c4+e];
    }
    // visibility covered by the prologue __syncthreads below
  }

  // ---- prologue: F2 slice -> registers via LDS (two halves) ----
  float2 fr[KYC];
  #pragma unroll
  for(int half=0; half<2; half++){
    for(int i=tid;i<1536;i+=256){
      int cc=i/96, q=i-cc*96;
      ((float4*)f2h)[i] = *((const float4*)(F2 + ((size_t)(b*WID + half*16 + cc)*NX + x)*(KYC*KT)) + q);
    }
    __syncthreads();
    if((cid>>4) == half){
      const float2* fp = f2h + (cid&15)*192 + ktid;
      #pragma unroll
      for(int ky=0;ky<KYC;ky++) fr[ky] = fp[ky*8];
    }
    __syncthreads();
  }
  // fold irfft-T scale (k==0?1:2)/NT into fr (linear through inv-Y)
  {
    float ts = (ktid==0 ? 1.0f : 2.0f) * (1.0f/(float)NT);
    #pragma unroll
    for(int ky=0;ky<KYC;ky++){ fr[ky].x *= ts; fr[ky].y *= ts; }
  }
  float wreg[WID];
  #pragma unroll
  for(int cc=0;cc<WID;cc++) wreg[cc] = wcv[oid*WID + cc];
  float breg = bcv[oid];
  // per-thread T-twiddle base: e^{i*pi/4*(k*tg mod 8)}  (t = 5*tg + j)
  float2 twtg[KT];
  #pragma unroll
  for(int k=0;k<KT;k++){
    float ang = 0.78539816339744831f*(float)((k*tg)&7);
    twtg[k] = make_float2(cosf(ang), sinf(ang));
  }
  for(int i=tid;i<32*KYC;i+=256){
    int yy=i/KYC, ky=i-yy*KYC;
    int f = ky<M1C ? ky : ky+40;
    float ang = TWO_PI*(float)((f*(y0+yy))%NY)/(float)NY;
    twy[i] = make_float2(cosf(ang)*(1.0f/64.0f), sinf(ang)*(1.0f/64.0f));
  }
  float* plane = V + (size_t)((b*NX+x)*NY + y0)*(NT*WID);
  const float4* gp = (const float4*)plane;
  const float* hbc = hin + (size_t)((b*NX+x)*NY + y0)*NT*2;
  const float* xbc = xin + (size_t)((b*NX+x)*NY + y0)*NT*3;
  bool has3 = tid < 128;
  // slot decomposition for LIFT staging: 640 f4-slots = [yy 2][t 40][c4 8]
  int t0c = tid>>3;                        // slot tid      (yy=0)
  int yy1c = (tid>=64);                    // slot tid+256
  int t1c = yy1c ? ((tid-64)>>3) : ((tid+256)>>3);
  int t2c = (tid+192)>>3;                  // slot tid+512  (yy=1, tid<128)
  int c4c = tid&7;                         // same c4 for all three slots

  float4 rA, rB, rC;                       // non-LIFT prefetch
  float2 hC0, hC1, hC2;                    // LIFT prefetch
  float xC00,xC01,xC02,xC10,xC11,xC12,xC20,xC21,xC22;

#define CV_LOAD(P) do{ \
    if constexpr(LIFT){ \
      { size_t pt = (size_t)((2*(P))*40 + t0c); \
        hC0 = *(const float2*)(hbc + pt*2); \
        xC00 = xbc[pt*3]; xC01 = xbc[pt*3+1]; xC02 = xbc[pt*3+2]; } \
      { size_t pt = (size_t)((2*(P)+yy1c)*40 + t1c); \
        hC1 = *(const float2*)(hbc + pt*2); \
        xC10 = xbc[pt*3]; xC11 = xbc[pt*3+1]; xC12 = xbc[pt*3+2]; } \
      if(has3){ size_t pt = (size_t)((2*(P)+1)*40 + t2c); \
        hC2 = *(const float2*)(hbc + pt*2); \
        xC20 = xbc[pt*3]; xC21 = xbc[pt*3+1]; xC22 = xbc[pt*3+2]; } \
    } else { \
      const float4* q = gp + (size_t)(P)*640; \
      rA = q[tid]; rB = q[256+tid]; \
      if(has3) rC = q[512+tid]; \
    } \
  }while(0)

#define CV_STAGE(BUF) do{ \
    if constexpr(LIFT){ \
      const float* wrp = wT2 + c4c*24; \
      float4 w0v = *(const float4*)(wrp); \
      float4 w1v = *(const float4*)(wrp+4); \
      float4 w2v = *(const float4*)(wrp+8); \
      float4 w3v = *(const float4*)(wrp+12); \
      float4 w4v = *(const float4*)(wrp+16); \
      float4 wbv = *(const float4*)(wrp+20); \
      float4 v0, v1, v2; \
      _Pragma("unroll") \
      for(int e=0;e<4;e++){ \
        float w0=((float*)&w0v)[e], w1=((float*)&w1v)[e], w2=((float*)&w2v)[e]; \
        float w3=((float*)&w3v)[e], w4=((float*)&w4v)[e], wb=((float*)&wbv)[e]; \
        ((float*)&v0)[e] = wb + hC0.x*w0 + hC0.y*w1 + xC00*w2 + xC01*w3 + xC02*w4; \
        ((float*)&v1)[e] = wb + hC1.x*w0 + hC1.y*w1 + xC10*w2 + xC11*w3 + xC12*w4; \
        if(has3) ((float*)&v2)[e] = wb + hC2.x*w0 + hC2.y*w1 + xC20*w2 + xC21*w3 + xC22*w4; \
      } \
      ((float4*)(BUF))[tid] = v0; \
      ((float4*)(BUF))[256+tid] = v1; \
      if(has3) ((float4*)(BUF))[512+tid] = v2; \
    } else { \
      ((float4*)(BUF))[tid] = rA; \
      ((float4*)(BUF))[256+tid] = rB; \
      if(has3) ((float4*)(BUF))[512+tid] = rC; \
    } \
  }while(0)

  // stage pair 0 into vtA; prefetch pair 1 into regs
  CV_LOAD(0);
  CV_STAGE(vtA);
  CV_LOAD(1);
  __syncthreads();                        // publish vtA + twy (+wT2) (prologue only)

  // cos/sin(pi*k*j/20) — compile-time literals (fold into v_fmac immediates)
  constexpr float CJ[KT][5] = {
    {1.f, 1.f,          1.f,          1.f,          1.f         },
    {1.f, 0.98768834f,  0.95105652f,  0.89100652f,  0.80901699f },
    {1.f, 0.95105652f,  0.80901699f,  0.58778525f,  0.30901699f },
    {1.f, 0.89100652f,  0.58778525f,  0.15643447f, -0.30901699f },
    {1.f, 0.80901699f,  0.30901699f, -0.30901699f, -0.80901699f },
    {1.f, 0.70710678f,  0.f,         -0.70710678f, -1.f         },
    {1.f, 0.58778525f, -0.30901699f, -0.95105652f, -0.80901699f },
    {1.f, 0.45399050f, -0.58778525f, -0.98768834f, -0.30901699f },
  };
  constexpr float SJ[KT][5] = {
    {0.f, 0.f,          0.f,          0.f,          0.f         },
    {0.f, 0.15643447f,  0.30901699f,  0.45399050f,  0.58778525f },
    {0.f, 0.30901699f,  0.58778525f,  0.80901699f,  0.95105652f },
    {0.f, 0.45399050f,  0.80901699f,  0.98768834f,  0.95105652f },
    {0.f, 0.58778525f,  0.95105652f,  0.95105652f,  0.58778525f },
    {0.f, 0.70710678f,  1.f,          0.70710678f,  0.f         },
    {0.f, 0.80901699f,  0.95105652f,  0.30901699f, -0.58778525f },
    {0.f, 0.89100652f,  0.80901699f, -0.15643447f, -0.95105652f },
  };

  #pragma unroll 1
  for(int it=0; it<16; ++it){
    float*  vcur = (it&1) ? vtB  : vtA;
    float*  vnxt = (it&1) ? vtA  : vtB;
    float2* fcur = (it&1) ? ftc1 : ftc0;
    int yl = it*2;
    { // inverse-Y for y=yl and yl+1, interleaved chains, b128 ky-pair twiddles
      const float2* tw0 = twy + (size_t)yl*KYC;
      const float2* tw1 = tw0 + KYC;
      float sr0=0.f, si0=0.f, sr1=0.f, si1=0.f;
      #pragma unroll
      for(int ky=0;ky<KYC;ky+=2){
        float2 a  = fr[ky];
        float2 b2 = fr[ky+1];
        float4 w0 = *(const float4*)&tw0[ky];
        float4 w1 = *(const float4*)&tw1[ky];
        sr0 += a.x*w0.x - a.y*w0.y + b2.x*w0.z - b2.y*w0.w;
        si0 += a.x*w0.y + a.y*w0.x + b2.x*w0.w + b2.y*w0.z;
        sr1 += a.x*w1.x - a.y*w1.y + b2.x*w1.z - b2.y*w1.w;
        si1 += a.x*w1.y + a.y*w1.x + b2.x*w1.w + b2.y*w1.z;
      }
      fcur[      ktid*32 + cid] = make_float2(sr0,si0);
      fcur[256 + ktid*32 + cid] = make_float2(sr1,si1);
    }
    barrier_lds();                        // the ONLY barrier per iteration
    // stage pair it+1 (regs -> vnxt) BEFORE this iteration's stores
    if(it+1 < 16){
      CV_STAGE(vnxt);
    }
    if(it+2 < 16){                        // issue loads for pair it+2
      CV_LOAD(it+2);
    }
    #pragma unroll
    for(int yy=0; yy<2; yy++){            // conv1x1 + irfft-T for the two y
      const float2* fsrc = fcur + yy*256;
      const float*  vb   = vcur + yy*1280;
      float* outp = plane + (size_t)(yl+yy)*(NT*WID);
      float acc[5];
      #pragma unroll
      for(int j=0;j<5;j++) acc[j] = breg;
      #pragma unroll
      for(int k=0;k<KT;k++){              // rotate mode by twtg, then literal DFT
        float2 f = fsrc[k*32 + oid];
        float gx = f.x*twtg[k].x - f.y*twtg[k].y;
        float gy = f.x*twtg[k].y + f.y*twtg[k].x;
        #pragma unroll
        for(int j=0;j<5;j++) acc[j] += gx*CJ[k][j] - gy*SJ[k][j];
      }
      #pragma unroll
      for(int j=0;j<5;j++){
        int t = tg*5 + j;
        float a = acc[j];
        const float* vrow = vb + t*32;
        #pragma unroll
        for(int c4=0;c4<WID;c4+=4){
          float4 vv = *(const float4*)(vrow + c4);   // broadcast b128
          a += vv.x*wreg[c4] + vv.y*wreg[c4+1] + vv.z*wreg[c4+2] + vv.w*wreg[c4+3];
        }
        outp[t*32 + oid] = GELU ? gelu_f(a) : a;     // lanes 0-31: one full 128B line
      }
    }
  }
#undef CV_LOAD
#undef CV_STAGE
}

// ---------------- fused fc1+gelu+fc2: V -> out [B,X,Y,T,2] ----------------
__global__ __launch_bounds__(256) void k_mlp(const float* __restrict__ V, const float* __restrict__ w1,
                                             const float* __restrict__ b1, const float* __restrict__ w2,
                                             const float* __restrict__ b2, float* __restrict__ out){
  __shared__ float sw1t[64*WID];          // [j][c]
  __shared__ float sb1[64], sw2[128], sb2[2];
  int tid=threadIdx.x;
  for(int i=tid;i<64*WID;i+=256){ int j=i>>5, c=i&31; sw1t[i]=w1[c*64+j]; }
  if(tid<64) sb1[tid]=b1[tid];
  if(tid<128) sw2[tid]=w2[tid];
  if(tid<2) sb2[tid]=b2[tid];
  __syncthreads();
  size_t p0 = (size_t)blockIdx.x*1024 + (size_t)tid*4;
  float vv[128];
  const float4* vp = (const float4*)(V + p0*WID);
  #pragma unroll
  for(int q=0;q<32;q++) *((float4*)(vv+4*q)) = vp[q];
  float oa[8];
  #pragma unroll
  for(int pt=0;pt<4;pt++){ oa[2*pt]=sb2[0]; oa[2*pt+1]=sb2[1]; }
  #pragma unroll 4
  for(int j=0;j<64;j++){
    float a0=sb1[j], a1=a0, a2=a0, a3=a0;
    const float* wrow = sw1t + j*WID;
    #pragma unroll
    for(int c4=0;c4<WID;c4+=4){
      float4 w = *(const float4*)(wrow + c4);        // broadcast b128
      a0 += vv[     c4]*w.x + vv[     c4+1]*w.y + vv[     c4+2]*w.z + vv[     c4+3]*w.w;
      a1 += vv[32 + c4]*w.x + vv[32 + c4+1]*w.y + vv[32 + c4+2]*w.z + vv[32 + c4+3]*w.w;
      a2 += vv[64 + c4]*w.x + vv[64 + c4+1]*w.y + vv[64 + c4+2]*w.z + vv[64 + c4+3]*w.w;
      a3 += vv[96 + c4]*w.x + vv[96 + c4+1]*w.y + vv[96 + c4+2]*w.z + vv[96 + c4+3]*w.w;
    }
    a0=gelu_f(a0); a1=gelu_f(a1); a2=gelu_f(a2); a3=gelu_f(a3);
    float u0=sw2[2*j], u1=sw2[2*j+1];
    oa[0]+=a0*u0; oa[1]+=a0*u1; oa[2]+=a1*u0; oa[3]+=a1*u1;
    oa[4]+=a2*u0; oa[5]+=a2*u1; oa[6]+=a3*u0; oa[7]+=a3*u1;
  }
  float4* op = (float4*)(out + p0*2);
  op[0]=make_float4(oa[0],oa[1],oa[2],oa[3]);
  op[1]=make_float4(oa[4],oa[5],oa[6],oa[7]);
}

extern "C" void kernel_launch(void* const* d_in, const int* in_sizes, int n_in,
                              void* d_out, int out_size, void* d_ws, size_t ws_size,
                              hipStream_t stream){
  const float* h     = (const float*)d_in[0];
  const float* x     = (const float*)d_in[1];
  const float* fc0_w = (const float*)d_in[2];
  const float* fc0_b = (const float*)d_in[3];
  const float* scwr[3] = {(const float*)d_in[4], (const float*)d_in[6], (const float*)d_in[8]};
  const float* scwi[3] = {(const float*)d_in[5], (const float*)d_in[7], (const float*)d_in[9]};
  const float* cw[3]   = {(const float*)d_in[10], (const float*)d_in[12], (const float*)d_in[14]};
  const float* cb[3]   = {(const float*)d_in[11], (const float*)d_in[13], (const float*)d_in[15]};
  const float* fc1_w = (const float*)d_in[16];
  const float* fc1_b = (const float*)d_in[17];
  const float* fc2_w = (const float*)d_in[18];
  const float* fc2_b = (const float*)d_in[19];

  // workspace: V (167.8 MB, layout [b,x,y,t,c]) | F2 (25.2 MB) | F4 (9.4 MB)
  // F3 lives in d_out (9.4 MB <= 10.5 MB) until k_mlp overwrites it.
  // R11: V is first written by k_conv L0 (fc0 lift fused into L0 consumers).
  const size_t VSZ = (size_t)BATCH*WID*NXYT;
  float*  V  = (float*)d_ws;
  float2* F2 = (float2*)(V + VSZ);
  float2* F4 = F2 + (size_t)BATCH*WID*NX*KYC*KT;
  float2* F3 = (float2*)d_out;

  for(int L=0; L<3; L++){
    if(L==0) k_fwd_ty<true ><<<BATCH*NX, 256, 0, stream>>>(V, F2, h, x, fc0_w, fc0_b);
    else     k_fwd_ty<false><<<BATCH*NX, 256, 0, stream>>>(V, F2, h, x, fc0_w, fc0_b);
    k_fwd_x<<<(BATCH*WID)*KYC, 256, 0, stream>>>(F2, F3);
    k_mix<<<KXC*KYC, 256, 0, stream>>>(F3, scwr[L], scwi[L], F4);
    k_inv_x<<<(BATCH*WID)*KYC, 256, 0, stream>>>(F4, F2);
    if(L==0)      k_conv<true ,true ><<<BATCH*NX*2, 256, 0, stream>>>(F2, cw[0], cb[0], V, h, x, fc0_w, fc0_b);
    else if(L==1) k_conv<true ,false><<<BATCH*NX*2, 256, 0, stream>>>(F2, cw[1], cb[1], V, h, x, fc0_w, fc0_b);
    else          k_conv<false,false><<<BATCH*NX*2, 256, 0, stream>>>(F2, cw[2], cb[2], V, h, x, fc0_w, fc0_b);
  }
  k_mlp<<<NP/1024, 256, 0, stream>>>(V, fc1_w, fc1_b, fc2_w, fc2_b, (float*)d_out);
}